// Round 3
// baseline (22771.716 us; speedup 1.0000x reference)
//
#include <hip/hip_runtime.h>

typedef float f32x4 __attribute__((ext_vector_type(4)));
typedef short s16x8 __attribute__((ext_vector_type(8)));
typedef short s16x4 __attribute__((ext_vector_type(4)));

namespace kf {
constexpr int TN = 1024, NS = 64, NO = 32, NI = 16;
constexpr int PP = 72;  // u16 pitch, 64-col bf16 arrays (dword granule 36 -> perfect bank packing)
constexpr int PK = 40;  // u16 pitch, 32-col bf16 arrays (granule 20 -> perfect)

constexpr float ATAB[6][5] = {
  {0.f,0.f,0.f,0.f,0.f},
  {(float)(1.0/5.0),0.f,0.f,0.f,0.f},
  {(float)(3.0/40.0),(float)(9.0/40.0),0.f,0.f,0.f},
  {(float)(44.0/45.0),(float)(-56.0/15.0),(float)(32.0/9.0),0.f,0.f},
  {(float)(19372.0/6561.0),(float)(-25360.0/2187.0),(float)(64448.0/6561.0),(float)(-212.0/729.0),0.f},
  {(float)(9017.0/3168.0),(float)(-355.0/33.0),(float)(46732.0/5247.0),(float)(49.0/176.0),(float)(-5103.0/18656.0)},
};
constexpr float CTAB[6] = {0.f,(float)(1.0/5.0),(float)(3.0/10.0),(float)(4.0/5.0),(float)(8.0/9.0),1.f};
constexpr float BW0=(float)(35.0/384.0), BW2=(float)(500.0/1113.0), BW3=(float)(125.0/192.0),
                BW4=(float)(-2187.0/6784.0), BW5=(float)(11.0/84.0);

struct Sh {
  unsigned short Pib[64*PP];   // S ~= Pi (written via transpose-pack; symmetric)
  unsigned short Ab [64*PP];   // A row-major bf16
  unsigned short Cb [32*PP];   // C row-major bf16
  unsigned short RCb[32*PP];   // Rinv@C row-major bf16
  unsigned short KKb[64*PK];   // KK = S Ct Rinv (gain), row-major
  unsigned short GTb[64*PK];   // GT = S Ct, row-major
  float Bf[64*16];             // B f32
  float XV[64]; float UV[16]; float CXR[32]; float AXB[64]; float AX2[64]; float FAC[32];
  float GJ[32*64];             // init scratch: Gauss-Jordan / layout-test reference
  int HYP;
};
} // namespace kf
using namespace kf;

__device__ inline float bf2f(unsigned short u){
  unsigned int x = ((unsigned int)u) << 16; return __builtin_bit_cast(float, x);
}
__device__ inline unsigned short f2bf(float f){
  unsigned int x = __builtin_bit_cast(unsigned int, f);
  return (unsigned short)((x + 0x7fffu + ((x >> 16) & 1u)) >> 16);
}
__device__ inline unsigned int pack2bf(float a, float b){
  return (unsigned int)f2bf(a) | ((unsigned int)f2bf(b) << 16);
}
// A/B fragment loader, mfma_f32_16x16x32_bf16, row-major bf16 source.
__device__ inline s16x8 load_frag(const unsigned short* arr, int pitch, int row0, int k0, int hyp){
  const int l = (int)(threadIdx.x & 63), lc = l & 15, lg = l >> 4;
  const unsigned short* p = arr + (row0 + lc) * pitch + k0;
  if ((hyp & 1) == 0) {
    return *(const s16x8*)(p + lg * 8);
  } else {
    s16x4 a = *(const s16x4*)(p + lg * 4);
    s16x4 b = *(const s16x4*)(p + 16 + lg * 4);
    s16x8 r; r[0]=a[0]; r[1]=a[1]; r[2]=a[2]; r[3]=a[3]; r[4]=b[0]; r[5]=b[1]; r[6]=b[2]; r[7]=b[3];
    return r;
  }
}
__device__ inline f32x4 MF(s16x8 a, s16x8 b, f32x4 c, int hyp){
  if (hyp & 2) return __builtin_amdgcn_mfma_f32_16x16x32_bf16(b, a, c, 0, 0, 0);
  return __builtin_amdgcn_mfma_f32_16x16x32_bf16(a, b, c, 0, 0, 0);
}
__device__ inline float dot8(s16x8 v, f32x4 a, f32x4 b){
  return bf2f(v[0])*a.x + bf2f(v[1])*a.y + bf2f(v[2])*a.z + bf2f(v[3])*a.w
       + bf2f(v[4])*b.x + bf2f(v[5])*b.y + bf2f(v[6])*b.z + bf2f(v[7])*b.w;
}
__device__ inline void interp_iw(float tcur, float cst, float t0, float h, int t, int& sel, float& w){
  float te = tcur + cst * h;
  float sf = (te - t0) / h;
  int i0 = (int)floorf(sf);
  i0 = i0 < 0 ? 0 : (i0 > TN - 2 ? TN - 2 : i0);
  w = sf - (float)i0;
  sel = i0 - t;
  if (sel < 0) { sel = 0; w = 0.f; }
  if (sel > 1) { sel = 1; w = 1.f; }
}

__global__ __launch_bounds__(512, 2)
void kf_mfma2(const float* __restrict__ ts, const float* __restrict__ ys,
              const float* __restrict__ us, const float* __restrict__ Ag,
              const float* __restrict__ Bg, const float* __restrict__ Cg,
              const float* __restrict__ x0g, const float* __restrict__ P0g,
              const float* __restrict__ Qg, const float* __restrict__ Rg,
              float* __restrict__ out)
{
  __shared__ Sh sh;
  const int tid = (int)threadIdx.x;
  const int wv = tid >> 6;       // wave 0..7
  const int l  = tid & 63;
  const int lc = l & 15, lg = l >> 4;

  // ===================== init =====================
  for (int idx = tid; idx < 64*64; idx += 512) sh.Ab[(idx>>6)*PP + (idx&63)] = f2bf(Ag[idx]);
  for (int idx = tid; idx < 32*64; idx += 512) sh.Cb[(idx>>6)*PP + (idx&63)] = f2bf(Cg[idx]);
  for (int idx = tid; idx < 64*16; idx += 512) sh.Bf[idx] = Bg[idx];
  for (int idx = tid; idx < 32*64; idx += 512) {
    int r = idx >> 6, c = idx & 63;
    sh.GJ[idx] = (c < 32) ? Rg[r*32 + c] : ((c - 32) == r ? 1.f : 0.f);
  }
  __syncthreads();
  for (int k2 = 0; k2 < 32; ++k2) {
    if (tid < 32) sh.FAC[tid] = sh.GJ[tid*64 + k2];
    __syncthreads();
    const float pinv = 1.f / sh.FAC[k2];
    float oldv[4], vk[4];
    #pragma unroll
    for (int s = 0; s < 4; ++s) {
      int idx = tid + s*512;
      oldv[s] = sh.GJ[idx];
      vk[s]   = sh.GJ[k2*64 + (idx & 63)];
    }
    __syncthreads();
    #pragma unroll
    for (int s = 0; s < 4; ++s) {
      int idx = tid + s*512, i = idx >> 6;
      sh.GJ[idx] = (i == k2) ? (oldv[s] * pinv) : (oldv[s] - sh.FAC[i] * (vk[s] * pinv));
    }
    __syncthreads();
  }
  for (int idx = tid; idx < 32*64; idx += 512) {   // RC = Rinv @ C
    int q = idx >> 6, k = idx & 63;
    float a = 0.f;
    for (int p = 0; p < 32; ++p) a += sh.GJ[q*64 + 32 + p] * Cg[p*64 + k];
    sh.RCb[q*PP + k] = f2bf(a);
  }
  __syncthreads();
  // fragment-layout reference: X[r][c] = sum_{k<32} A[r][k]*A[16+c][k]  (asymmetric, swap-detecting)
  if (tid < 256) {
    int r = tid >> 4, c = tid & 15;
    float a = 0.f;
    for (int k = 0; k < 32; ++k) a += bf2f(sh.Ab[r*PP + k]) * bf2f(sh.Ab[(16 + c)*PP + k]);
    sh.GJ[tid] = a;
  }
  if (tid == 0) sh.HYP = -1;
  __syncthreads();
  for (int hh = 0; hh < 4; ++hh) {
    if (wv == 0) {
      s16x8 af = load_frag(sh.Ab, PP, 0, 0, hh);
      s16x8 bf = load_frag(sh.Ab, PP, 16, 0, hh);
      f32x4 z = {0.f,0.f,0.f,0.f};
      f32x4 d = MF(af, bf, z, hh);
      int ok = 1;
      #pragma unroll
      for (int r = 0; r < 4; ++r) {
        float rf = sh.GJ[(lg*4 + r)*16 + lc];
        ok &= (fabsf(d[r] - rf) <= 1e-3f + 1e-2f * fabsf(rf)) ? 1 : 0;
      }
      if (__all(ok) && tid == 0) { if (sh.HYP < 0) sh.HYP = hh; }
    }
    __syncthreads();
  }
  const int sHyp = (sh.HYP < 0) ? 0 : sh.HYP;

  // ===================== persistent state =====================
  const float t0 = ts[0];
  const float h  = ts[1] - t0;
  f32x4 z4 = {0.f,0.f,0.f,0.f};
  f32x4 Pfr[4], Qfr[4], kP[6][4], APd[4], APT[4];
  s16x8 aA[2], bA[4][2], aRC[2][2], aC[2][2];
  float xr = 0.f, kxr[6];
  float u0=0.f,u1=0.f,u2=0.f, y0=0.f,y1=0.f,y2=0.f;
  #pragma unroll
  for (int j = 0; j < 6; ++j) { kxr[j] = 0.f; }
  #pragma unroll
  for (int ct = 0; ct < 4; ++ct) { Pfr[ct]=z4; Qfr[ct]=z4; APd[ct]=z4; APT[ct]=z4; }
  #pragma unroll
  for (int j = 0; j < 6; ++j)
    #pragma unroll
    for (int ct = 0; ct < 4; ++ct) kP[j][ct] = z4;

  if (wv < 4) {
    #pragma unroll
    for (int ct = 0; ct < 4; ++ct)
      #pragma unroll
      for (int r = 0; r < 4; ++r) {
        int row = 16*wv + 4*lg + r, col = 16*ct + lc;
        Pfr[ct][r] = P0g[row*64 + col];
        Qfr[ct][r] = Qg [row*64 + col];
      }
    aA[0] = load_frag(sh.Ab, PP, 16*wv, 0,  sHyp);
    aA[1] = load_frag(sh.Ab, PP, 16*wv, 32, sHyp);
    #pragma unroll
    for (int ct = 0; ct < 4; ++ct)
      #pragma unroll
      for (int kb = 0; kb < 2; ++kb) bA[ct][kb] = load_frag(sh.Ab, PP, 16*ct, 32*kb, sHyp);
  } else {
    #pragma unroll
    for (int rt = 0; rt < 2; ++rt)
      #pragma unroll
      for (int kb = 0; kb < 2; ++kb) {
        aRC[rt][kb] = load_frag(sh.RCb, PP, 16*rt, 32*kb, sHyp);
        aC [rt][kb] = load_frag(sh.Cb,  PP, 16*rt, 32*kb, sHyp);
      }
  }
  if (wv == 4) { xr = x0g[l]; out[l] = xr; }
  if (wv == 5) { y0 = ys[l & 31]; y1 = ys[NO + (l & 31)]; }
  if (wv == 6) { u0 = us[l & 15]; u1 = us[NI + (l & 15)]; }
  __syncthreads();

  // ===================== main scan =====================
  for (int t = 0; t < TN - 1; ++t) {
    float tcur = 0.f;
    if (wv == 5) { tcur = ts[t]; if (t + 2 < TN) y2 = ys[(t+2)*NO + (l & 31)]; }
    if (wv == 6) { tcur = ts[t]; if (t + 2 < TN) u2 = us[(t+2)*NI + (l & 15)]; }
    #pragma unroll
    for (int st = 0; st < 6; ++st) {
      // ======== PHASE A ========
      if (wv < 4) {
        if (t > 0 || st > 0) {
          const int ps = (st == 0) ? 5 : st - 1;
          s16x8 am = load_frag(sh.KKb, PK, 16*wv, 0, sHyp);
          #pragma unroll
          for (int ct = 0; ct < 4; ++ct) {
            s16x8 bg = load_frag(sh.GTb, PK, 16*ct, 0, sHyp);
            f32x4 M = MF(am, bg, z4, sHyp);
            #pragma unroll
            for (int r = 0; r < 4; ++r)
              kP[ps][ct][r] = APd[ct][r] + APT[ct][r] - M[r];
          }
        }
        #pragma unroll
        for (int ct = 0; ct < 4; ++ct) {
          float v[4];
          #pragma unroll
          for (int r = 0; r < 4; ++r) {
            float x;
            if (st == 0) {
              if (t > 0)
                Pfr[ct][r] += h * (BW0*kP[0][ct][r] + BW2*kP[2][ct][r] + BW3*kP[3][ct][r]
                                 + BW4*kP[4][ct][r] + BW5*kP[5][ct][r] + Qfr[ct][r]);
              x = Pfr[ct][r];
            } else {
              x = Pfr[ct][r] + (h * CTAB[st]) * Qfr[ct][r];
              #pragma unroll
              for (int j = 0; j < 5; ++j)
                if (ATAB[st][j] != 0.f) x += (h * ATAB[st][j]) * kP[j][ct][r];
            }
            v[r] = x;
          }
          uint2 pk; pk.x = pack2bf(v[0], v[1]); pk.y = pack2bf(v[2], v[3]);
          *(uint2*)&sh.Pib[(16*ct + lc)*PP + 16*wv + 4*lg] = pk;   // transpose-pack (Pi sym)
        }
      } else if (wv == 4) {
        if (t > 0 || st > 0) {
          const int ps = (st == 0) ? 5 : st - 1;
          float kx = sh.AXB[l] + sh.AX2[l];
          const f32x4* cx4 = (const f32x4*)sh.CXR;
          #pragma unroll
          for (int ch = 0; ch < 4; ++ch) {
            s16x8 kv = *(const s16x8*)&sh.KKb[l*PK + ch*8];
            kx += dot8(kv, cx4[2*ch], cx4[2*ch + 1]);
          }
          kxr[ps] = kx;
        }
        float xi;
        if (st == 0) {
          if (t > 0) {
            xr += h * (BW0*kxr[0] + BW2*kxr[2] + BW3*kxr[3] + BW4*kxr[4] + BW5*kxr[5]);
            out[t*64 + l] = xr;
          }
          xi = xr;
        } else {
          xi = xr;
          #pragma unroll
          for (int j = 0; j < 5; ++j)
            if (ATAB[st][j] != 0.f) xi += (h * ATAB[st][j]) * kxr[j];
        }
        sh.XV[l] = xi;
      } else if (wv == 6) {
        int sel; float w;
        interp_iw(tcur, CTAB[st], t0, h, t, sel, w);
        float ua = sel ? u1 : u0, ub = sel ? u2 : u1;
        if (l < 16) sh.UV[l] = ua * (1.f - w) + ub * w;
      }
      __syncthreads();
      // ======== PHASE B ========
      if (wv < 4) {
        s16x8 bP0[4], bP1[4];
        #pragma unroll
        for (int ct = 0; ct < 4; ++ct) {
          bP0[ct] = load_frag(sh.Pib, PP, 16*ct, 0,  sHyp);
          bP1[ct] = load_frag(sh.Pib, PP, 16*ct, 32, sHyp);
        }
        s16x8 aPi0 = load_frag(sh.Pib, PP, 16*wv, 0,  sHyp);
        s16x8 aPi1 = load_frag(sh.Pib, PP, 16*wv, 32, sHyp);
        #pragma unroll
        for (int ct = 0; ct < 4; ++ct) {
          f32x4 acc = MF(aA[0], bP0[ct], z4, sHyp);
          APd[ct] = MF(aA[1], bP1[ct], acc, sHyp);
          f32x4 acc2 = MF(aPi0, bA[ct][0], z4, sHyp);
          APT[ct] = MF(aPi1, bA[ct][1], acc2, sHyp);
        }
      } else {
        const int g = wv - 4;
        s16x8 bPi0 = load_frag(sh.Pib, PP, 16*g, 0,  sHyp);
        s16x8 bPi1 = load_frag(sh.Pib, PP, 16*g, 32, sHyp);
        #pragma unroll
        for (int rt = 0; rt < 2; ++rt) {
          f32x4 aK = MF(aRC[rt][0], bPi0, z4, sHyp);
          aK = MF(aRC[rt][1], bPi1, aK, sHyp);
          uint2 pkk; pkk.x = pack2bf(aK[0], aK[1]); pkk.y = pack2bf(aK[2], aK[3]);
          *(uint2*)&sh.KKb[(16*g + lc)*PK + 16*rt + 4*lg] = pkk;
          f32x4 aG = MF(aC[rt][0], bPi0, z4, sHyp);
          aG = MF(aC[rt][1], bPi1, aG, sHyp);
          uint2 pkg; pkg.x = pack2bf(aG[0], aG[1]); pkg.y = pack2bf(aG[2], aG[3]);
          *(uint2*)&sh.GTb[(16*g + lc)*PK + 16*rt + 4*lg] = pkg;
        }
        if (wv == 5) {
          const int qq = l & 31, hf = l >> 5;
          float cx = 0.f;
          const f32x4* xv4 = (const f32x4*)&sh.XV[32*hf];
          #pragma unroll
          for (int ch = 0; ch < 4; ++ch) {
            s16x8 cvv = *(const s16x8*)&sh.Cb[qq*PP + 32*hf + 8*ch];
            cx += dot8(cvv, xv4[2*ch], xv4[2*ch + 1]);
          }
          cx += __shfl_xor(cx, 32);
          int sel; float w;
          interp_iw(tcur, CTAB[st], t0, h, t, sel, w);
          float ya = sel ? y1 : y0, yb = sel ? y2 : y1;
          if (l < 32) sh.CXR[l] = (ya * (1.f - w) + yb * w) - cx;
        } else if (wv == 6) {
          float ax = 0.f;
          const f32x4* xv4 = (const f32x4*)sh.XV;
          #pragma unroll
          for (int ch = 0; ch < 4; ++ch) {
            s16x8 av = *(const s16x8*)&sh.Ab[l*PP + 8*ch];
            ax += dot8(av, xv4[2*ch], xv4[2*ch + 1]);
          }
          float bu = 0.f;
          const f32x4* bf4 = (const f32x4*)&sh.Bf[l*16];
          const f32x4* uv4 = (const f32x4*)sh.UV;
          #pragma unroll
          for (int ch = 0; ch < 4; ++ch) {
            f32x4 b = bf4[ch], u = uv4[ch];
            bu += b.x*u.x + b.y*u.y + b.z*u.z + b.w*u.w;
          }
          sh.AXB[l] = ax + bu;
        } else if (wv == 7) {
          float ax = 0.f;
          const f32x4* xv4 = (const f32x4*)&sh.XV[32];
          #pragma unroll
          for (int ch = 0; ch < 4; ++ch) {
            s16x8 av = *(const s16x8*)&sh.Ab[l*PP + 32 + 8*ch];
            ax += dot8(av, xv4[2*ch], xv4[2*ch + 1]);
          }
          sh.AX2[l] = ax;
        }
      }
      __syncthreads();
    } // stages
    u0 = u1; u1 = u2; y0 = y1; y1 = y2;
  } // t

  // tail: slope 5 of last step + final combine
  if (wv == 4) {
    float kx = sh.AXB[l] + sh.AX2[l];
    const f32x4* cx4 = (const f32x4*)sh.CXR;
    #pragma unroll
    for (int ch = 0; ch < 4; ++ch) {
      s16x8 kv = *(const s16x8*)&sh.KKb[l*PK + ch*8];
      kx += dot8(kv, cx4[2*ch], cx4[2*ch + 1]);
    }
    kxr[5] = kx;
    xr += h * (BW0*kxr[0] + BW2*kxr[2] + BW3*kxr[3] + BW4*kxr[4] + BW5*kxr[5]);
    out[(TN - 1)*64 + l] = xr;
  }
}

extern "C" void kernel_launch(void* const* d_in, const int* in_sizes, int n_in,
                              void* d_out, int out_size, void* d_ws, size_t ws_size,
                              hipStream_t stream) {
  (void)in_sizes; (void)n_in; (void)out_size; (void)d_ws; (void)ws_size;
  const float* ts  = (const float*)d_in[0];
  const float* ys  = (const float*)d_in[1];
  const float* us  = (const float*)d_in[2];
  const float* A   = (const float*)d_in[3];
  const float* B   = (const float*)d_in[4];
  const float* C   = (const float*)d_in[5];
  const float* x0  = (const float*)d_in[6];
  const float* P0  = (const float*)d_in[7];
  const float* Q   = (const float*)d_in[8];
  const float* R   = (const float*)d_in[9];
  hipLaunchKernelGGL(kf_mfma2, dim3(1), dim3(512), 0, stream,
                     ts, ys, us, A, B, C, x0, P0, Q, R, (float*)d_out);
}

// Round 4
// 18592.598 us; speedup vs baseline: 1.2248x; 1.2248x over previous
//
#include <hip/hip_runtime.h>

typedef float f32x4 __attribute__((ext_vector_type(4)));
typedef short s16x8 __attribute__((ext_vector_type(8)));
typedef short s16x4 __attribute__((ext_vector_type(4)));

namespace kf {
constexpr int TN = 1024, NS = 64, NO = 32, NI = 16;
constexpr int PP = 72;  // u16 pitch, 64-col bf16 arrays (16B-granule stride 9 == 1 mod 8 -> conflict-free b128 frags)
constexpr int PK = 40;  // u16 pitch, 32-col bf16 arrays (granule stride 5 -> conflict-free)

constexpr float ATAB[6][5] = {
  {0.f,0.f,0.f,0.f,0.f},
  {(float)(1.0/5.0),0.f,0.f,0.f,0.f},
  {(float)(3.0/40.0),(float)(9.0/40.0),0.f,0.f,0.f},
  {(float)(44.0/45.0),(float)(-56.0/15.0),(float)(32.0/9.0),0.f,0.f},
  {(float)(19372.0/6561.0),(float)(-25360.0/2187.0),(float)(64448.0/6561.0),(float)(-212.0/729.0),0.f},
  {(float)(9017.0/3168.0),(float)(-355.0/33.0),(float)(46732.0/5247.0),(float)(49.0/176.0),(float)(-5103.0/18656.0)},
};
constexpr float CTAB[6] = {0.f,(float)(1.0/5.0),(float)(3.0/10.0),(float)(4.0/5.0),(float)(8.0/9.0),1.f};
constexpr float BW0=(float)(35.0/384.0), BW2=(float)(500.0/1113.0), BW3=(float)(125.0/192.0),
                BW4=(float)(-2187.0/6784.0), BW5=(float)(11.0/84.0);

struct Sh {
  unsigned short Pib[64*PP];   // Pi (written via transpose-pack; symmetric)
  unsigned short Ab [64*PP];   // A row-major bf16
  unsigned short Cb [32*PP];   // C row-major bf16
  unsigned short RCb[32*PP];   // Rinv@C row-major bf16
  unsigned short KKb[64*PK];   // KK = Pi Ct Rinv (gain), row-major
  unsigned short GTb[64*PK];   // GT = Pi Ct, row-major
  float Bf[64*16];             // B f32
  float XV[64]; float UV[16]; float CXR[32]; float AXB[64]; float AX2[64]; float FAC[32];
  float GJ[32*64];             // init scratch: Gauss-Jordan / layout-test reference
  int HYP;
};
} // namespace kf
using namespace kf;

__device__ inline float bf2f(unsigned short u){
  unsigned int x = ((unsigned int)u) << 16; return __builtin_bit_cast(float, x);
}
__device__ inline unsigned short f2bf(float f){
  unsigned int x = __builtin_bit_cast(unsigned int, f);
  return (unsigned short)((x + 0x7fffu + ((x >> 16) & 1u)) >> 16);
}
__device__ inline unsigned int pack2bf(float a, float b){
  return (unsigned int)f2bf(a) | ((unsigned int)f2bf(b) << 16);
}
// ---- runtime-hyp versions (init-time layout probe only) ----
__device__ inline s16x8 load_frag(const unsigned short* arr, int pitch, int row0, int k0, int hyp){
  const int l = (int)(threadIdx.x & 63), lc = l & 15, lg = l >> 4;
  const unsigned short* p = arr + (row0 + lc) * pitch + k0;
  if ((hyp & 1) == 0) {
    return *(const s16x8*)(p + lg * 8);
  } else {
    s16x4 a = *(const s16x4*)(p + lg * 4);
    s16x4 b = *(const s16x4*)(p + 16 + lg * 4);
    s16x8 r; r[0]=a[0]; r[1]=a[1]; r[2]=a[2]; r[3]=a[3]; r[4]=b[0]; r[5]=b[1]; r[6]=b[2]; r[7]=b[3];
    return r;
  }
}
__device__ inline f32x4 MF(s16x8 a, s16x8 b, f32x4 c, int hyp){
  if (hyp & 2) return __builtin_amdgcn_mfma_f32_16x16x32_bf16(b, a, c, 0, 0, 0);
  return __builtin_amdgcn_mfma_f32_16x16x32_bf16(a, b, c, 0, 0, 0);
}
// ---- compile-time-hyp versions (hot loop) ----
template<int HYP>
__device__ inline s16x8 load_fragT(const unsigned short* arr, int pitch, int row0, int k0){
  const int l = (int)(threadIdx.x & 63), lc = l & 15, lg = l >> 4;
  const unsigned short* p = arr + (row0 + lc) * pitch + k0;
  if constexpr ((HYP & 1) == 0) {
    return *(const s16x8*)(p + lg * 8);
  } else {
    s16x4 a = *(const s16x4*)(p + lg * 4);
    s16x4 b = *(const s16x4*)(p + 16 + lg * 4);
    s16x8 r; r[0]=a[0]; r[1]=a[1]; r[2]=a[2]; r[3]=a[3]; r[4]=b[0]; r[5]=b[1]; r[6]=b[2]; r[7]=b[3];
    return r;
  }
}
template<int HYP>
__device__ inline f32x4 MFT(s16x8 a, s16x8 b, f32x4 c){
  if constexpr ((HYP & 2) != 0) return __builtin_amdgcn_mfma_f32_16x16x32_bf16(b, a, c, 0, 0, 0);
  else                          return __builtin_amdgcn_mfma_f32_16x16x32_bf16(a, b, c, 0, 0, 0);
}
__device__ inline float dot8(s16x8 v, f32x4 a, f32x4 b){
  return bf2f(v[0])*a.x + bf2f(v[1])*a.y + bf2f(v[2])*a.z + bf2f(v[3])*a.w
       + bf2f(v[4])*b.x + bf2f(v[5])*b.y + bf2f(v[6])*b.z + bf2f(v[7])*b.w;
}
__device__ inline void interp_iw(float tcur, float cst, float t0, float h, int t, int& sel, float& w){
  float te = tcur + cst * h;
  float sf = (te - t0) / h;
  int i0 = (int)floorf(sf);
  i0 = i0 < 0 ? 0 : (i0 > TN - 2 ? TN - 2 : i0);
  w = sf - (float)i0;
  sel = i0 - t;
  if (sel < 0) { sel = 0; w = 0.f; }
  if (sel > 1) { sel = 1; w = 1.f; }
}

template<int HYP>
__device__ __noinline__ void scan_body(Sh& sh,
    const float* __restrict__ ts, const float* __restrict__ ys, const float* __restrict__ us,
    const float* __restrict__ x0g, const float* __restrict__ P0g, const float* __restrict__ Qg,
    float* __restrict__ out)
{
  const int tid = (int)threadIdx.x;
  const int wv = tid >> 6;       // wave 0..7
  const int l  = tid & 63;
  const int lc = l & 15, lg = l >> 4;

  const float t0 = ts[0];
  const float h  = ts[1] - t0;
  f32x4 z4 = {0.f,0.f,0.f,0.f};
  f32x4 Pfr[4], Qfr[4], kP[6][4], APd[4], APT[4];
  s16x8 aA[2], bA[4][2], aRC[2][2], aC[2][2];
  float xr = 0.f, kxr[6];
  float u0=0.f,u1=0.f,u2=0.f, y0=0.f,y1=0.f,y2=0.f;
  #pragma unroll
  for (int j = 0; j < 6; ++j) kxr[j] = 0.f;
  #pragma unroll
  for (int ct = 0; ct < 4; ++ct) { Pfr[ct]=z4; Qfr[ct]=z4; APd[ct]=z4; APT[ct]=z4; }
  #pragma unroll
  for (int j = 0; j < 6; ++j)
    #pragma unroll
    for (int ct = 0; ct < 4; ++ct) kP[j][ct] = z4;

  if (wv < 4) {
    #pragma unroll
    for (int ct = 0; ct < 4; ++ct)
      #pragma unroll
      for (int r = 0; r < 4; ++r) {
        int row = 16*wv + 4*lg + r, col = 16*ct + lc;
        Pfr[ct][r] = P0g[row*64 + col];
        Qfr[ct][r] = Qg [row*64 + col];
      }
    aA[0] = load_fragT<HYP>(sh.Ab, PP, 16*wv, 0);
    aA[1] = load_fragT<HYP>(sh.Ab, PP, 16*wv, 32);
    #pragma unroll
    for (int ct = 0; ct < 4; ++ct)
      #pragma unroll
      for (int kb = 0; kb < 2; ++kb) bA[ct][kb] = load_fragT<HYP>(sh.Ab, PP, 16*ct, 32*kb);
  } else {
    #pragma unroll
    for (int rt = 0; rt < 2; ++rt)
      #pragma unroll
      for (int kb = 0; kb < 2; ++kb) {
        aRC[rt][kb] = load_fragT<HYP>(sh.RCb, PP, 16*rt, 32*kb);
        aC [rt][kb] = load_fragT<HYP>(sh.Cb,  PP, 16*rt, 32*kb);
      }
  }
  if (wv == 4) { xr = x0g[l]; out[l] = xr; }
  if (wv == 5) { y0 = ys[l & 31]; y1 = ys[NO + (l & 31)]; }
  if (wv == 6) { u0 = us[l & 15]; u1 = us[NI + (l & 15)]; }
  __syncthreads();

  for (int t = 0; t < TN - 1; ++t) {
    float tcur = 0.f;
    if (wv == 5) { tcur = ts[t]; if (t + 2 < TN) y2 = ys[(t+2)*NO + (l & 31)]; }
    if (wv == 6) { tcur = ts[t]; if (t + 2 < TN) u2 = us[(t+2)*NI + (l & 15)]; }
    #pragma unroll
    for (int st = 0; st < 6; ++st) {
      // ======== PHASE A: finish prev slope (M via MFMA), stage combine, pack Pi ========
      if (wv < 4) {
        if (t > 0 || st > 0) {
          const int ps = (st == 0) ? 5 : st - 1;
          s16x8 am = load_fragT<HYP>(sh.KKb, PK, 16*wv, 0);
          #pragma unroll
          for (int ct = 0; ct < 4; ++ct) {
            s16x8 bg = load_fragT<HYP>(sh.GTb, PK, 16*ct, 0);
            f32x4 M = MFT<HYP>(am, bg, z4);
            #pragma unroll
            for (int r = 0; r < 4; ++r)
              kP[ps][ct][r] = APd[ct][r] + APT[ct][r] - M[r];
          }
        }
        #pragma unroll
        for (int ct = 0; ct < 4; ++ct) {
          float v[4];
          #pragma unroll
          for (int r = 0; r < 4; ++r) {
            float x;
            if (st == 0) {
              if (t > 0)
                Pfr[ct][r] += h * (BW0*kP[0][ct][r] + BW2*kP[2][ct][r] + BW3*kP[3][ct][r]
                                 + BW4*kP[4][ct][r] + BW5*kP[5][ct][r] + Qfr[ct][r]);
              x = Pfr[ct][r];
            } else {
              x = Pfr[ct][r] + (h * CTAB[st]) * Qfr[ct][r];
              #pragma unroll
              for (int j = 0; j < 5; ++j)
                if (ATAB[st][j] != 0.f) x += (h * ATAB[st][j]) * kP[j][ct][r];
            }
            v[r] = x;
          }
          uint2 pk; pk.x = pack2bf(v[0], v[1]); pk.y = pack2bf(v[2], v[3]);
          *(uint2*)&sh.Pib[(16*ct + lc)*PP + 16*wv + 4*lg] = pk;   // transpose-pack (Pi sym)
        }
      } else if (wv == 4) {
        if (t > 0 || st > 0) {
          const int ps = (st == 0) ? 5 : st - 1;
          float kx = sh.AXB[l] + sh.AX2[l];
          const f32x4* cx4 = (const f32x4*)sh.CXR;
          #pragma unroll
          for (int ch = 0; ch < 4; ++ch) {
            s16x8 kv = *(const s16x8*)&sh.KKb[l*PK + ch*8];
            kx += dot8(kv, cx4[2*ch], cx4[2*ch + 1]);
          }
          kxr[ps] = kx;
        }
        float xi;
        if (st == 0) {
          if (t > 0) {
            xr += h * (BW0*kxr[0] + BW2*kxr[2] + BW3*kxr[3] + BW4*kxr[4] + BW5*kxr[5]);
            out[t*64 + l] = xr;
          }
          xi = xr;
        } else {
          xi = xr;
          #pragma unroll
          for (int j = 0; j < 5; ++j)
            if (ATAB[st][j] != 0.f) xi += (h * ATAB[st][j]) * kxr[j];
        }
        sh.XV[l] = xi;
      } else if (wv == 6) {
        int sel; float w;
        interp_iw(tcur, CTAB[st], t0, h, t, sel, w);
        float ua = sel ? u1 : u0, ub = sel ? u2 : u1;
        if (l < 16) sh.UV[l] = ua * (1.f - w) + ub * w;
      }
      __syncthreads();
      // ======== PHASE B: APd/APT (w0-3) | KK,GT + x-vec work (w4-7) ========
      if (wv < 4) {
        s16x8 bP0[4], bP1[4];
        #pragma unroll
        for (int ct = 0; ct < 4; ++ct) {
          bP0[ct] = load_fragT<HYP>(sh.Pib, PP, 16*ct, 0);
          bP1[ct] = load_fragT<HYP>(sh.Pib, PP, 16*ct, 32);
        }
        s16x8 aPi0 = load_fragT<HYP>(sh.Pib, PP, 16*wv, 0);
        s16x8 aPi1 = load_fragT<HYP>(sh.Pib, PP, 16*wv, 32);
        #pragma unroll
        for (int ct = 0; ct < 4; ++ct) {
          f32x4 acc = MFT<HYP>(aA[0], bP0[ct], z4);
          APd[ct] = MFT<HYP>(aA[1], bP1[ct], acc);
          f32x4 acc2 = MFT<HYP>(aPi0, bA[ct][0], z4);
          APT[ct] = MFT<HYP>(aPi1, bA[ct][1], acc2);
        }
      } else {
        const int g = wv - 4;
        s16x8 bPi0 = load_fragT<HYP>(sh.Pib, PP, 16*g, 0);
        s16x8 bPi1 = load_fragT<HYP>(sh.Pib, PP, 16*g, 32);
        #pragma unroll
        for (int rt = 0; rt < 2; ++rt) {
          f32x4 aK = MFT<HYP>(aRC[rt][0], bPi0, z4);
          aK = MFT<HYP>(aRC[rt][1], bPi1, aK);
          uint2 pkk; pkk.x = pack2bf(aK[0], aK[1]); pkk.y = pack2bf(aK[2], aK[3]);
          *(uint2*)&sh.KKb[(16*g + lc)*PK + 16*rt + 4*lg] = pkk;
          f32x4 aG = MFT<HYP>(aC[rt][0], bPi0, z4);
          aG = MFT<HYP>(aC[rt][1], bPi1, aG);
          uint2 pkg; pkg.x = pack2bf(aG[0], aG[1]); pkg.y = pack2bf(aG[2], aG[3]);
          *(uint2*)&sh.GTb[(16*g + lc)*PK + 16*rt + 4*lg] = pkg;
        }
        if (wv == 5) {
          const int qq = l & 31, hf = l >> 5;
          float cx = 0.f;
          const f32x4* xv4 = (const f32x4*)&sh.XV[32*hf];
          #pragma unroll
          for (int ch = 0; ch < 4; ++ch) {
            s16x8 cvv = *(const s16x8*)&sh.Cb[qq*PP + 32*hf + 8*ch];
            cx += dot8(cvv, xv4[2*ch], xv4[2*ch + 1]);
          }
          cx += __shfl_xor(cx, 32);
          int sel; float w;
          interp_iw(tcur, CTAB[st], t0, h, t, sel, w);
          float ya = sel ? y1 : y0, yb = sel ? y2 : y1;
          if (l < 32) sh.CXR[l] = (ya * (1.f - w) + yb * w) - cx;
        } else if (wv == 6) {
          float ax = 0.f;
          const f32x4* xv4 = (const f32x4*)sh.XV;
          #pragma unroll
          for (int ch = 0; ch < 4; ++ch) {
            s16x8 av = *(const s16x8*)&sh.Ab[l*PP + 8*ch];
            ax += dot8(av, xv4[2*ch], xv4[2*ch + 1]);
          }
          float bu = 0.f;
          const f32x4* bf4 = (const f32x4*)&sh.Bf[l*16];
          const f32x4* uv4 = (const f32x4*)sh.UV;
          #pragma unroll
          for (int ch = 0; ch < 4; ++ch) {
            f32x4 b = bf4[ch], u = uv4[ch];
            bu += b.x*u.x + b.y*u.y + b.z*u.z + b.w*u.w;
          }
          sh.AXB[l] = ax + bu;
        } else if (wv == 7) {
          float ax = 0.f;
          const f32x4* xv4 = (const f32x4*)&sh.XV[32];
          #pragma unroll
          for (int ch = 0; ch < 4; ++ch) {
            s16x8 av = *(const s16x8*)&sh.Ab[l*PP + 32 + 8*ch];
            ax += dot8(av, xv4[2*ch], xv4[2*ch + 1]);
          }
          sh.AX2[l] = ax;
        }
      }
      __syncthreads();
    } // stages
    u0 = u1; u1 = u2; y0 = y1; y1 = y2;
  } // t

  // tail: slope 5 of last step + final combine
  if (wv == 4) {
    float kx = sh.AXB[l] + sh.AX2[l];
    const f32x4* cx4 = (const f32x4*)sh.CXR;
    #pragma unroll
    for (int ch = 0; ch < 4; ++ch) {
      s16x8 kv = *(const s16x8*)&sh.KKb[l*PK + ch*8];
      kx += dot8(kv, cx4[2*ch], cx4[2*ch + 1]);
    }
    kxr[5] = kx;
    xr += h * (BW0*kxr[0] + BW2*kxr[2] + BW3*kxr[3] + BW4*kxr[4] + BW5*kxr[5]);
    out[(TN - 1)*64 + l] = xr;
  }
}

__global__ __launch_bounds__(512, 1)
void kf_mfma3(const float* __restrict__ ts, const float* __restrict__ ys,
              const float* __restrict__ us, const float* __restrict__ Ag,
              const float* __restrict__ Bg, const float* __restrict__ Cg,
              const float* __restrict__ x0g, const float* __restrict__ P0g,
              const float* __restrict__ Qg, const float* __restrict__ Rg,
              float* __restrict__ out)
{
  __shared__ Sh sh;
  const int tid = (int)threadIdx.x;
  const int wv = tid >> 6;
  const int lc = tid & 15, lg = (tid & 63) >> 4;

  // ===================== init =====================
  for (int idx = tid; idx < 64*64; idx += 512) sh.Ab[(idx>>6)*PP + (idx&63)] = f2bf(Ag[idx]);
  for (int idx = tid; idx < 32*64; idx += 512) sh.Cb[(idx>>6)*PP + (idx&63)] = f2bf(Cg[idx]);
  for (int idx = tid; idx < 64*16; idx += 512) sh.Bf[idx] = Bg[idx];
  for (int idx = tid; idx < 32*64; idx += 512) {
    int r = idx >> 6, c = idx & 63;
    sh.GJ[idx] = (c < 32) ? Rg[r*32 + c] : ((c - 32) == r ? 1.f : 0.f);
  }
  __syncthreads();
  for (int k2 = 0; k2 < 32; ++k2) {
    if (tid < 32) sh.FAC[tid] = sh.GJ[tid*64 + k2];
    __syncthreads();
    const float pinv = 1.f / sh.FAC[k2];
    float oldv[4], vk[4];
    #pragma unroll
    for (int s = 0; s < 4; ++s) {
      int idx = tid + s*512;
      oldv[s] = sh.GJ[idx];
      vk[s]   = sh.GJ[k2*64 + (idx & 63)];
    }
    __syncthreads();
    #pragma unroll
    for (int s = 0; s < 4; ++s) {
      int idx = tid + s*512, i = idx >> 6;
      sh.GJ[idx] = (i == k2) ? (oldv[s] * pinv) : (oldv[s] - sh.FAC[i] * (vk[s] * pinv));
    }
    __syncthreads();
  }
  for (int idx = tid; idx < 32*64; idx += 512) {   // RC = Rinv @ C
    int q = idx >> 6, k = idx & 63;
    float a = 0.f;
    for (int p = 0; p < 32; ++p) a += sh.GJ[q*64 + 32 + p] * Cg[p*64 + k];
    sh.RCb[q*PP + k] = f2bf(a);
  }
  __syncthreads();
  // fragment-layout reference: X[r][c] = sum_{k<32} A[r][k]*A[16+c][k]  (asymmetric, swap-detecting)
  if (tid < 256) {
    int r = tid >> 4, c = tid & 15;
    float a = 0.f;
    for (int k = 0; k < 32; ++k) a += bf2f(sh.Ab[r*PP + k]) * bf2f(sh.Ab[(16 + c)*PP + k]);
    sh.GJ[tid] = a;
  }
  if (tid == 0) sh.HYP = -1;
  __syncthreads();
  for (int hh = 0; hh < 4; ++hh) {
    if (wv == 0) {
      s16x8 af = load_frag(sh.Ab, PP, 0, 0, hh);
      s16x8 bf = load_frag(sh.Ab, PP, 16, 0, hh);
      f32x4 z = {0.f,0.f,0.f,0.f};
      f32x4 d = MF(af, bf, z, hh);
      int ok = 1;
      #pragma unroll
      for (int r = 0; r < 4; ++r) {
        float rf = sh.GJ[(lg*4 + r)*16 + lc];
        ok &= (fabsf(d[r] - rf) <= 1e-3f + 1e-2f * fabsf(rf)) ? 1 : 0;
      }
      if (__all(ok) && tid == 0) { if (sh.HYP < 0) sh.HYP = hh; }
    }
    __syncthreads();
  }
  const int sHyp = (sh.HYP < 0) ? 0 : sh.HYP;

  switch (sHyp) {
    case 0: scan_body<0>(sh, ts, ys, us, x0g, P0g, Qg, out); break;
    case 1: scan_body<1>(sh, ts, ys, us, x0g, P0g, Qg, out); break;
    case 2: scan_body<2>(sh, ts, ys, us, x0g, P0g, Qg, out); break;
    default: scan_body<3>(sh, ts, ys, us, x0g, P0g, Qg, out); break;
  }
}

extern "C" void kernel_launch(void* const* d_in, const int* in_sizes, int n_in,
                              void* d_out, int out_size, void* d_ws, size_t ws_size,
                              hipStream_t stream) {
  (void)in_sizes; (void)n_in; (void)out_size; (void)d_ws; (void)ws_size;
  const float* ts  = (const float*)d_in[0];
  const float* ys  = (const float*)d_in[1];
  const float* us  = (const float*)d_in[2];
  const float* A   = (const float*)d_in[3];
  const float* B   = (const float*)d_in[4];
  const float* C   = (const float*)d_in[5];
  const float* x0  = (const float*)d_in[6];
  const float* P0  = (const float*)d_in[7];
  const float* Q   = (const float*)d_in[8];
  const float* R   = (const float*)d_in[9];
  hipLaunchKernelGGL(kf_mfma3, dim3(1), dim3(512), 0, stream,
                     ts, ys, us, A, B, C, x0, P0, Q, R, (float*)d_out);
}

// Round 5
// 14679.225 us; speedup vs baseline: 1.5513x; 1.2666x over previous
//
#include <hip/hip_runtime.h>

typedef float f32x4 __attribute__((ext_vector_type(4)));
typedef short s16x8 __attribute__((ext_vector_type(8)));
typedef short s16x4 __attribute__((ext_vector_type(4)));

namespace kf {
constexpr int TN = 1024, NS = 64, NO = 32, NI = 16;
constexpr int PP = 72;  // u16 pitch, 64-col bf16 arrays (16B-granule stride 9 -> conflict-free b128 frags)
constexpr int PK = 40;  // u16 pitch, 32-col bf16 arrays (granule stride 5 -> conflict-free)

constexpr float ATAB[6][5] = {
  {0.f,0.f,0.f,0.f,0.f},
  {(float)(1.0/5.0),0.f,0.f,0.f,0.f},
  {(float)(3.0/40.0),(float)(9.0/40.0),0.f,0.f,0.f},
  {(float)(44.0/45.0),(float)(-56.0/15.0),(float)(32.0/9.0),0.f,0.f},
  {(float)(19372.0/6561.0),(float)(-25360.0/2187.0),(float)(64448.0/6561.0),(float)(-212.0/729.0),0.f},
  {(float)(9017.0/3168.0),(float)(-355.0/33.0),(float)(46732.0/5247.0),(float)(49.0/176.0),(float)(-5103.0/18656.0)},
};
constexpr float CTAB[6] = {0.f,(float)(1.0/5.0),(float)(3.0/10.0),(float)(4.0/5.0),(float)(8.0/9.0),1.f};
constexpr float BW0=(float)(35.0/384.0), BW2=(float)(500.0/1113.0), BW3=(float)(125.0/192.0),
                BW4=(float)(-2187.0/6784.0), BW5=(float)(11.0/84.0);

struct Sh {
  unsigned short Pib[64*PP];   // Pi (written via transpose-pack; symmetric)
  unsigned short Ab [64*PP];   // A row-major bf16
  unsigned short Cb [32*PP];   // C row-major bf16
  unsigned short RCb[32*PP];   // Rinv@C row-major bf16
  unsigned short KKb[64*PK];   // KK = Pi Ct Rinv (gain), row-major
  unsigned short GTb[64*PK];   // GT = Pi Ct, row-major
  float Bf[64*16];             // B f32
  float XV[64]; float UV[16]; float CXR[32]; float AXB[64]; float AX2[64]; float FAC[32];
  float GJ[32*64];             // init scratch: Gauss-Jordan / layout-test reference
  int HYP;
};
} // namespace kf
using namespace kf;

__device__ inline float bf2f(unsigned short u){
  unsigned int x = ((unsigned int)u) << 16; return __builtin_bit_cast(float, x);
}
__device__ inline unsigned short f2bf(float f){
  unsigned int x = __builtin_bit_cast(unsigned int, f);
  return (unsigned short)((x + 0x7fffu + ((x >> 16) & 1u)) >> 16);
}
__device__ inline unsigned int pack2bf(float a, float b){
  return (unsigned int)f2bf(a) | ((unsigned int)f2bf(b) << 16);
}
// ---- runtime-hyp versions (init-time layout probe only) ----
__device__ inline s16x8 load_frag(const unsigned short* arr, int pitch, int row0, int k0, int hyp){
  const int l = (int)(threadIdx.x & 63), lc = l & 15, lg = l >> 4;
  const unsigned short* p = arr + (row0 + lc) * pitch + k0;
  if ((hyp & 1) == 0) {
    return *(const s16x8*)(p + lg * 8);
  } else {
    s16x4 a = *(const s16x4*)(p + lg * 4);
    s16x4 b = *(const s16x4*)(p + 16 + lg * 4);
    s16x8 r; r[0]=a[0]; r[1]=a[1]; r[2]=a[2]; r[3]=a[3]; r[4]=b[0]; r[5]=b[1]; r[6]=b[2]; r[7]=b[3];
    return r;
  }
}
__device__ inline f32x4 MF(s16x8 a, s16x8 b, f32x4 c, int hyp){
  if (hyp & 2) return __builtin_amdgcn_mfma_f32_16x16x32_bf16(b, a, c, 0, 0, 0);
  return __builtin_amdgcn_mfma_f32_16x16x32_bf16(a, b, c, 0, 0, 0);
}
// ---- compile-time-hyp versions (hot loop) ----
template<int HYP>
__device__ __forceinline__ s16x8 load_fragT(const unsigned short* arr, int pitch, int row0, int k0){
  const int l = (int)(threadIdx.x & 63), lc = l & 15, lg = l >> 4;
  const unsigned short* p = arr + (row0 + lc) * pitch + k0;
  if constexpr ((HYP & 1) == 0) {
    return *(const s16x8*)(p + lg * 8);
  } else {
    s16x4 a = *(const s16x4*)(p + lg * 4);
    s16x4 b = *(const s16x4*)(p + 16 + lg * 4);
    s16x8 r; r[0]=a[0]; r[1]=a[1]; r[2]=a[2]; r[3]=a[3]; r[4]=b[0]; r[5]=b[1]; r[6]=b[2]; r[7]=b[3];
    return r;
  }
}
template<int HYP>
__device__ __forceinline__ f32x4 MFT(s16x8 a, s16x8 b, f32x4 c){
  if constexpr ((HYP & 2) != 0) return __builtin_amdgcn_mfma_f32_16x16x32_bf16(b, a, c, 0, 0, 0);
  else                          return __builtin_amdgcn_mfma_f32_16x16x32_bf16(a, b, c, 0, 0, 0);
}
__device__ inline float dot8(s16x8 v, f32x4 a, f32x4 b){
  return bf2f(v[0])*a.x + bf2f(v[1])*a.y + bf2f(v[2])*a.z + bf2f(v[3])*a.w
       + bf2f(v[4])*b.x + bf2f(v[5])*b.y + bf2f(v[6])*b.z + bf2f(v[7])*b.w;
}
__device__ inline void interp_iw(float tcur, float cst, float t0, float h, int t, int& sel, float& w){
  float te = tcur + cst * h;
  float sf = (te - t0) / h;
  int i0 = (int)floorf(sf);
  i0 = i0 < 0 ? 0 : (i0 > TN - 2 ? TN - 2 : i0);
  w = sf - (float)i0;
  sel = i0 - t;
  if (sel < 0) { sel = 0; w = 0.f; }
  if (sel > 1) { sel = 1; w = 1.f; }
}

// NOTE: __forceinline__ is load-bearing. As a __noinline__ device function this
// body is register-allocated for default flat_work_group_size(1..1024) -> hard
// 128-VGPR cap -> kP[6][4] spills to scratch (R2-R4: VGPR_Count=128, ~500KB
// spill WRITE traffic, 73% latency idle). Inlined, it inherits
// __launch_bounds__(512,1): 8 waves/wg = 2 waves/SIMD -> 256-VGPR budget.
template<int HYP>
__device__ __forceinline__ void scan_body(Sh& sh,
    const float* __restrict__ ts, const float* __restrict__ ys, const float* __restrict__ us,
    const float* __restrict__ x0g, const float* __restrict__ P0g, const float* __restrict__ Qg,
    float* __restrict__ out)
{
  const int tid = (int)threadIdx.x;
  const int wv = tid >> 6;       // wave 0..7
  const int l  = tid & 63;
  const int lc = l & 15, lg = l >> 4;

  const float t0 = ts[0];
  const float h  = ts[1] - t0;
  f32x4 z4 = {0.f,0.f,0.f,0.f};
  f32x4 Pfr[4], Qfr[4], kP[6][4], APd[4], APT[4];
  s16x8 aA[2], aRC[2][2], aC[2][2];
  float xr = 0.f, kxr[6];
  float u0=0.f,u1=0.f,u2=0.f, y0=0.f,y1=0.f,y2=0.f;
  #pragma unroll
  for (int j = 0; j < 6; ++j) kxr[j] = 0.f;
  #pragma unroll
  for (int ct = 0; ct < 4; ++ct) { Pfr[ct]=z4; Qfr[ct]=z4; APd[ct]=z4; APT[ct]=z4; }
  #pragma unroll
  for (int j = 0; j < 6; ++j)
    #pragma unroll
    for (int ct = 0; ct < 4; ++ct) kP[j][ct] = z4;

  if (wv < 4) {
    #pragma unroll
    for (int ct = 0; ct < 4; ++ct)
      #pragma unroll
      for (int r = 0; r < 4; ++r) {
        int row = 16*wv + 4*lg + r, col = 16*ct + lc;
        Pfr[ct][r] = P0g[row*64 + col];
        Qfr[ct][r] = Qg [row*64 + col];
      }
    aA[0] = load_fragT<HYP>(sh.Ab, PP, 16*wv, 0);
    aA[1] = load_fragT<HYP>(sh.Ab, PP, 16*wv, 32);
  } else {
    #pragma unroll
    for (int rt = 0; rt < 2; ++rt)
      #pragma unroll
      for (int kb = 0; kb < 2; ++kb) {
        aRC[rt][kb] = load_fragT<HYP>(sh.RCb, PP, 16*rt, 32*kb);
        aC [rt][kb] = load_fragT<HYP>(sh.Cb,  PP, 16*rt, 32*kb);
      }
  }
  if (wv == 4) { xr = x0g[l]; out[l] = xr; }
  if (wv == 5) { y0 = ys[l & 31]; y1 = ys[NO + (l & 31)]; }
  if (wv == 6) { u0 = us[l & 15]; u1 = us[NI + (l & 15)]; }
  __syncthreads();

  for (int t = 0; t < TN - 1; ++t) {
    float tcur = 0.f;
    if (wv == 5) { tcur = ts[t]; if (t + 2 < TN) y2 = ys[(t+2)*NO + (l & 31)]; }
    if (wv == 6) { tcur = ts[t]; if (t + 2 < TN) u2 = us[(t+2)*NI + (l & 15)]; }
    #pragma unroll
    for (int st = 0; st < 6; ++st) {
      // ======== PHASE A: finish prev slope (M via MFMA), stage combine, pack Pi ========
      if (wv < 4) {
        if (t > 0 || st > 0) {
          const int ps = (st == 0) ? 5 : st - 1;
          s16x8 am = load_fragT<HYP>(sh.KKb, PK, 16*wv, 0);
          #pragma unroll
          for (int ct = 0; ct < 4; ++ct) {
            s16x8 bg = load_fragT<HYP>(sh.GTb, PK, 16*ct, 0);
            f32x4 M = MFT<HYP>(am, bg, z4);
            #pragma unroll
            for (int r = 0; r < 4; ++r)
              kP[ps][ct][r] = APd[ct][r] + APT[ct][r] - M[r];
          }
        }
        #pragma unroll
        for (int ct = 0; ct < 4; ++ct) {
          float v[4];
          #pragma unroll
          for (int r = 0; r < 4; ++r) {
            float x;
            if (st == 0) {
              if (t > 0)
                Pfr[ct][r] += h * (BW0*kP[0][ct][r] + BW2*kP[2][ct][r] + BW3*kP[3][ct][r]
                                 + BW4*kP[4][ct][r] + BW5*kP[5][ct][r] + Qfr[ct][r]);
              x = Pfr[ct][r];
            } else {
              x = Pfr[ct][r] + (h * CTAB[st]) * Qfr[ct][r];
              #pragma unroll
              for (int j = 0; j < 5; ++j)
                if (ATAB[st][j] != 0.f) x += (h * ATAB[st][j]) * kP[j][ct][r];
            }
            v[r] = x;
          }
          uint2 pk; pk.x = pack2bf(v[0], v[1]); pk.y = pack2bf(v[2], v[3]);
          *(uint2*)&sh.Pib[(16*ct + lc)*PP + 16*wv + 4*lg] = pk;   // transpose-pack (Pi sym)
        }
      } else if (wv == 4) {
        if (t > 0 || st > 0) {
          const int ps = (st == 0) ? 5 : st - 1;
          float kx = sh.AXB[l] + sh.AX2[l];
          const f32x4* cx4 = (const f32x4*)sh.CXR;
          #pragma unroll
          for (int ch = 0; ch < 4; ++ch) {
            s16x8 kv = *(const s16x8*)&sh.KKb[l*PK + ch*8];
            kx += dot8(kv, cx4[2*ch], cx4[2*ch + 1]);
          }
          kxr[ps] = kx;
        }
        float xi;
        if (st == 0) {
          if (t > 0) {
            xr += h * (BW0*kxr[0] + BW2*kxr[2] + BW3*kxr[3] + BW4*kxr[4] + BW5*kxr[5]);
            out[t*64 + l] = xr;
          }
          xi = xr;
        } else {
          xi = xr;
          #pragma unroll
          for (int j = 0; j < 5; ++j)
            if (ATAB[st][j] != 0.f) xi += (h * ATAB[st][j]) * kxr[j];
        }
        sh.XV[l] = xi;
      } else if (wv == 6) {
        int sel; float w;
        interp_iw(tcur, CTAB[st], t0, h, t, sel, w);
        float ua = sel ? u1 : u0, ub = sel ? u2 : u1;
        if (l < 16) sh.UV[l] = ua * (1.f - w) + ub * w;
      }
      __syncthreads();
      // ======== PHASE B: APd/APT (w0-3) | KK,GT + x-vec work (w4-7) ========
      if (wv < 4) {
        s16x8 aPi0 = load_fragT<HYP>(sh.Pib, PP, 16*wv, 0);
        s16x8 aPi1 = load_fragT<HYP>(sh.Pib, PP, 16*wv, 32);
        #pragma unroll
        for (int ct = 0; ct < 4; ++ct) {
          s16x8 bP0 = load_fragT<HYP>(sh.Pib, PP, 16*ct, 0);
          s16x8 bP1 = load_fragT<HYP>(sh.Pib, PP, 16*ct, 32);
          s16x8 bA0 = load_fragT<HYP>(sh.Ab,  PP, 16*ct, 0);
          s16x8 bA1 = load_fragT<HYP>(sh.Ab,  PP, 16*ct, 32);
          f32x4 acc = MFT<HYP>(aA[0], bP0, z4);
          APd[ct] = MFT<HYP>(aA[1], bP1, acc);
          f32x4 acc2 = MFT<HYP>(aPi0, bA0, z4);
          APT[ct] = MFT<HYP>(aPi1, bA1, acc2);
        }
      } else {
        const int g = wv - 4;
        s16x8 bPi0 = load_fragT<HYP>(sh.Pib, PP, 16*g, 0);
        s16x8 bPi1 = load_fragT<HYP>(sh.Pib, PP, 16*g, 32);
        #pragma unroll
        for (int rt = 0; rt < 2; ++rt) {
          f32x4 aK = MFT<HYP>(aRC[rt][0], bPi0, z4);
          aK = MFT<HYP>(aRC[rt][1], bPi1, aK);
          uint2 pkk; pkk.x = pack2bf(aK[0], aK[1]); pkk.y = pack2bf(aK[2], aK[3]);
          *(uint2*)&sh.KKb[(16*g + lc)*PK + 16*rt + 4*lg] = pkk;
          f32x4 aG = MFT<HYP>(aC[rt][0], bPi0, z4);
          aG = MFT<HYP>(aC[rt][1], bPi1, aG);
          uint2 pkg; pkg.x = pack2bf(aG[0], aG[1]); pkg.y = pack2bf(aG[2], aG[3]);
          *(uint2*)&sh.GTb[(16*g + lc)*PK + 16*rt + 4*lg] = pkg;
        }
        if (wv == 5) {
          const int qq = l & 31, hf = l >> 5;
          float cx = 0.f;
          const f32x4* xv4 = (const f32x4*)&sh.XV[32*hf];
          #pragma unroll
          for (int ch = 0; ch < 4; ++ch) {
            s16x8 cvv = *(const s16x8*)&sh.Cb[qq*PP + 32*hf + 8*ch];
            cx += dot8(cvv, xv4[2*ch], xv4[2*ch + 1]);
          }
          cx += __shfl_xor(cx, 32);
          int sel; float w;
          interp_iw(tcur, CTAB[st], t0, h, t, sel, w);
          float ya = sel ? y1 : y0, yb = sel ? y2 : y1;
          if (l < 32) sh.CXR[l] = (ya * (1.f - w) + yb * w) - cx;
        } else if (wv == 6) {
          float ax = 0.f;
          const f32x4* xv4 = (const f32x4*)sh.XV;
          #pragma unroll
          for (int ch = 0; ch < 4; ++ch) {
            s16x8 av = *(const s16x8*)&sh.Ab[l*PP + 8*ch];
            ax += dot8(av, xv4[2*ch], xv4[2*ch + 1]);
          }
          float bu = 0.f;
          const f32x4* bf4 = (const f32x4*)&sh.Bf[l*16];
          const f32x4* uv4 = (const f32x4*)sh.UV;
          #pragma unroll
          for (int ch = 0; ch < 4; ++ch) {
            f32x4 b = bf4[ch], u = uv4[ch];
            bu += b.x*u.x + b.y*u.y + b.z*u.z + b.w*u.w;
          }
          sh.AXB[l] = ax + bu;
        } else if (wv == 7) {
          float ax = 0.f;
          const f32x4* xv4 = (const f32x4*)&sh.XV[32];
          #pragma unroll
          for (int ch = 0; ch < 4; ++ch) {
            s16x8 av = *(const s16x8*)&sh.Ab[l*PP + 32 + 8*ch];
            ax += dot8(av, xv4[2*ch], xv4[2*ch + 1]);
          }
          sh.AX2[l] = ax;
        }
      }
      __syncthreads();
    } // stages
    u0 = u1; u1 = u2; y0 = y1; y1 = y2;
  } // t

  // tail: slope 5 of last step + final combine
  if (wv == 4) {
    float kx = sh.AXB[l] + sh.AX2[l];
    const f32x4* cx4 = (const f32x4*)sh.CXR;
    #pragma unroll
    for (int ch = 0; ch < 4; ++ch) {
      s16x8 kv = *(const s16x8*)&sh.KKb[l*PK + ch*8];
      kx += dot8(kv, cx4[2*ch], cx4[2*ch + 1]);
    }
    kxr[5] = kx;
    xr += h * (BW0*kxr[0] + BW2*kxr[2] + BW3*kxr[3] + BW4*kxr[4] + BW5*kxr[5]);
    out[(TN - 1)*64 + l] = xr;
  }
}

__global__ __launch_bounds__(512, 1)
void kf_mfma4(const float* __restrict__ ts, const float* __restrict__ ys,
              const float* __restrict__ us, const float* __restrict__ Ag,
              const float* __restrict__ Bg, const float* __restrict__ Cg,
              const float* __restrict__ x0g, const float* __restrict__ P0g,
              const float* __restrict__ Qg, const float* __restrict__ Rg,
              float* __restrict__ out)
{
  __shared__ Sh sh;
  const int tid = (int)threadIdx.x;
  const int wv = tid >> 6;
  const int lc = tid & 15, lg = (tid & 63) >> 4;

  // ===================== init =====================
  for (int idx = tid; idx < 64*64; idx += 512) sh.Ab[(idx>>6)*PP + (idx&63)] = f2bf(Ag[idx]);
  for (int idx = tid; idx < 32*64; idx += 512) sh.Cb[(idx>>6)*PP + (idx&63)] = f2bf(Cg[idx]);
  for (int idx = tid; idx < 64*16; idx += 512) sh.Bf[idx] = Bg[idx];
  for (int idx = tid; idx < 32*64; idx += 512) {
    int r = idx >> 6, c = idx & 63;
    sh.GJ[idx] = (c < 32) ? Rg[r*32 + c] : ((c - 32) == r ? 1.f : 0.f);
  }
  __syncthreads();
  for (int k2 = 0; k2 < 32; ++k2) {
    if (tid < 32) sh.FAC[tid] = sh.GJ[tid*64 + k2];
    __syncthreads();
    const float pinv = 1.f / sh.FAC[k2];
    float oldv[4], vk[4];
    #pragma unroll
    for (int s = 0; s < 4; ++s) {
      int idx = tid + s*512;
      oldv[s] = sh.GJ[idx];
      vk[s]   = sh.GJ[k2*64 + (idx & 63)];
    }
    __syncthreads();
    #pragma unroll
    for (int s = 0; s < 4; ++s) {
      int idx = tid + s*512, i = idx >> 6;
      sh.GJ[idx] = (i == k2) ? (oldv[s] * pinv) : (oldv[s] - sh.FAC[i] * (vk[s] * pinv));
    }
    __syncthreads();
  }
  for (int idx = tid; idx < 32*64; idx += 512) {   // RC = Rinv @ C
    int q = idx >> 6, k = idx & 63;
    float a = 0.f;
    for (int p = 0; p < 32; ++p) a += sh.GJ[q*64 + 32 + p] * Cg[p*64 + k];
    sh.RCb[q*PP + k] = f2bf(a);
  }
  __syncthreads();
  // fragment-layout reference: X[r][c] = sum_{k<32} A[r][k]*A[16+c][k]  (asymmetric, swap-detecting)
  if (tid < 256) {
    int r = tid >> 4, c = tid & 15;
    float a = 0.f;
    for (int k = 0; k < 32; ++k) a += bf2f(sh.Ab[r*PP + k]) * bf2f(sh.Ab[(16 + c)*PP + k]);
    sh.GJ[tid] = a;
  }
  if (tid == 0) sh.HYP = -1;
  __syncthreads();
  for (int hh = 0; hh < 4; ++hh) {
    if (wv == 0) {
      s16x8 af = load_frag(sh.Ab, PP, 0, 0, hh);
      s16x8 bf = load_frag(sh.Ab, PP, 16, 0, hh);
      f32x4 z = {0.f,0.f,0.f,0.f};
      f32x4 d = MF(af, bf, z, hh);
      int ok = 1;
      #pragma unroll
      for (int r = 0; r < 4; ++r) {
        float rf = sh.GJ[(lg*4 + r)*16 + lc];
        ok &= (fabsf(d[r] - rf) <= 1e-3f + 1e-2f * fabsf(rf)) ? 1 : 0;
      }
      if (__all(ok) && tid == 0) { if (sh.HYP < 0) sh.HYP = hh; }
    }
    __syncthreads();
  }
  const int sHyp = (sh.HYP < 0) ? 0 : sh.HYP;

  switch (sHyp) {
    case 0: scan_body<0>(sh, ts, ys, us, x0g, P0g, Qg, out); break;
    case 1: scan_body<1>(sh, ts, ys, us, x0g, P0g, Qg, out); break;
    case 2: scan_body<2>(sh, ts, ys, us, x0g, P0g, Qg, out); break;
    default: scan_body<3>(sh, ts, ys, us, x0g, P0g, Qg, out); break;
  }
}

extern "C" void kernel_launch(void* const* d_in, const int* in_sizes, int n_in,
                              void* d_out, int out_size, void* d_ws, size_t ws_size,
                              hipStream_t stream) {
  (void)in_sizes; (void)n_in; (void)out_size; (void)d_ws; (void)ws_size;
  const float* ts  = (const float*)d_in[0];
  const float* ys  = (const float*)d_in[1];
  const float* us  = (const float*)d_in[2];
  const float* A   = (const float*)d_in[3];
  const float* B   = (const float*)d_in[4];
  const float* C   = (const float*)d_in[5];
  const float* x0  = (const float*)d_in[6];
  const float* P0  = (const float*)d_in[7];
  const float* Q   = (const float*)d_in[8];
  const float* R   = (const float*)d_in[9];
  hipLaunchKernelGGL(kf_mfma4, dim3(1), dim3(512), 0, stream,
                     ts, ys, us, A, B, C, x0, P0, Q, R, (float*)d_out);
}

// Round 6
// 12142.168 us; speedup vs baseline: 1.8754x; 1.2089x over previous
//
#include <hip/hip_runtime.h>

typedef float f32x4 __attribute__((ext_vector_type(4)));
typedef short s16x8 __attribute__((ext_vector_type(8)));
typedef short s16x4 __attribute__((ext_vector_type(4)));

namespace kf {
constexpr int TN = 1024, NS = 64, NO = 32, NI = 16;
constexpr int PP = 72;  // u16 pitch, 64-col bf16 arrays (conflict-free b128 frags)
constexpr int PK = 40;  // u16 pitch, 32-col bf16 arrays (conflict-free)

constexpr float ATAB[6][5] = {
  {0.f,0.f,0.f,0.f,0.f},
  {(float)(1.0/5.0),0.f,0.f,0.f,0.f},
  {(float)(3.0/40.0),(float)(9.0/40.0),0.f,0.f,0.f},
  {(float)(44.0/45.0),(float)(-56.0/15.0),(float)(32.0/9.0),0.f,0.f},
  {(float)(19372.0/6561.0),(float)(-25360.0/2187.0),(float)(64448.0/6561.0),(float)(-212.0/729.0),0.f},
  {(float)(9017.0/3168.0),(float)(-355.0/33.0),(float)(46732.0/5247.0),(float)(49.0/176.0),(float)(-5103.0/18656.0)},
};
constexpr float CTAB[6] = {0.f,(float)(1.0/5.0),(float)(3.0/10.0),(float)(4.0/5.0),(float)(8.0/9.0),1.f};
constexpr float BW0=(float)(35.0/384.0), BW2=(float)(500.0/1113.0), BW3=(float)(125.0/192.0),
                BW4=(float)(-2187.0/6784.0), BW5=(float)(11.0/84.0);

struct Sh {
  unsigned short Pib[64*PP];   // Pi (transpose-packed; symmetric)
  unsigned short Ab [64*PP];   // A row-major bf16
  unsigned short Cb [32*PP];   // C row-major bf16
  unsigned short RCb[32*PP];   // Rinv@C row-major bf16
  unsigned short KKb[64*PK];   // KK = Pi Ct Rinv (gain), row-major
  unsigned short GTb[64*PK];   // GT = Pi Ct, row-major
  float Bf[64*16];             // B f32
  float XV[2][64];             // stage state xi, double-buffered on stage parity
  float UV[2][16];             // interp u, double-buffered
  float CXR[32];               // y_interp - C@xi
  float XR[64];                // running x state
  float kxs[5][64];            // x slopes k0..k4 (k5 consumed from registers)
  float FAC[32];
  float GJ[32*64];             // init scratch
  int HYP;
};
} // namespace kf
using namespace kf;

__device__ inline float bf2f(unsigned short u){
  unsigned int x = ((unsigned int)u) << 16; return __builtin_bit_cast(float, x);
}
__device__ inline unsigned short f2bf(float f){
  unsigned int x = __builtin_bit_cast(unsigned int, f);
  return (unsigned short)((x + 0x7fffu + ((x >> 16) & 1u)) >> 16);
}
__device__ inline unsigned int pack2bf(float a, float b){
  return (unsigned int)f2bf(a) | ((unsigned int)f2bf(b) << 16);
}
// ---- runtime-hyp versions (init-time layout probe only) ----
__device__ inline s16x8 load_frag(const unsigned short* arr, int pitch, int row0, int k0, int hyp){
  const int l = (int)(threadIdx.x & 63), lc = l & 15, lg = l >> 4;
  const unsigned short* p = arr + (row0 + lc) * pitch + k0;
  if ((hyp & 1) == 0) {
    return *(const s16x8*)(p + lg * 8);
  } else {
    s16x4 a = *(const s16x4*)(p + lg * 4);
    s16x4 b = *(const s16x4*)(p + 16 + lg * 4);
    s16x8 r; r[0]=a[0]; r[1]=a[1]; r[2]=a[2]; r[3]=a[3]; r[4]=b[0]; r[5]=b[1]; r[6]=b[2]; r[7]=b[3];
    return r;
  }
}
__device__ inline f32x4 MF(s16x8 a, s16x8 b, f32x4 c, int hyp){
  if (hyp & 2) return __builtin_amdgcn_mfma_f32_16x16x32_bf16(b, a, c, 0, 0, 0);
  return __builtin_amdgcn_mfma_f32_16x16x32_bf16(a, b, c, 0, 0, 0);
}
// ---- compile-time-hyp versions (hot loop) ----
template<int HYP>
__device__ __forceinline__ s16x8 load_fragT(const unsigned short* arr, int pitch, int row0, int k0){
  const int l = (int)(threadIdx.x & 63), lc = l & 15, lg = l >> 4;
  const unsigned short* p = arr + (row0 + lc) * pitch + k0;
  if constexpr ((HYP & 1) == 0) {
    return *(const s16x8*)(p + lg * 8);
  } else {
    s16x4 a = *(const s16x4*)(p + lg * 4);
    s16x4 b = *(const s16x4*)(p + 16 + lg * 4);
    s16x8 r; r[0]=a[0]; r[1]=a[1]; r[2]=a[2]; r[3]=a[3]; r[4]=b[0]; r[5]=b[1]; r[6]=b[2]; r[7]=b[3];
    return r;
  }
}
template<int HYP>
__device__ __forceinline__ f32x4 MFT(s16x8 a, s16x8 b, f32x4 c){
  if constexpr ((HYP & 2) != 0) return __builtin_amdgcn_mfma_f32_16x16x32_bf16(b, a, c, 0, 0, 0);
  else                          return __builtin_amdgcn_mfma_f32_16x16x32_bf16(a, b, c, 0, 0, 0);
}
__device__ inline float dot8(s16x8 v, f32x4 a, f32x4 b){
  return bf2f(v[0])*a.x + bf2f(v[1])*a.y + bf2f(v[2])*a.z + bf2f(v[3])*a.w
       + bf2f(v[4])*b.x + bf2f(v[5])*b.y + bf2f(v[6])*b.z + bf2f(v[7])*b.w;
}
__device__ inline void interp_iw(float tcur, float cst, float t0, float h, int t, int& sel, float& w){
  float te = tcur + cst * h;
  float sf = (te - t0) / h;
  int i0 = (int)floorf(sf);
  i0 = i0 < 0 ? 0 : (i0 > TN - 2 ? TN - 2 : i0);
  w = sf - (float)i0;
  sel = i0 - t;
  if (sel < 0) { sel = 0; w = 0.f; }
  if (sel > 1) { sel = 1; w = 1.f; }
}

// REGISTER-BUDGET NOTE (R2-R5 evidence): any 512-thread workgroup on gfx950 is
// hard-capped at ~128 arch VGPRs (2 waves/SIMD must fit the unified VGPR+AGPR
// file) -> kP[6][4] spilled to scratch in every 8-wave variant regardless of
// __launch_bounds__. 256-thread workgroups (R0/R1) allocated 192 with zero
// spill. So: 4 waves, each doing its P-strip MFMAs + KK/GT share + 1/4 of the
// x-side vector work.
template<int HYP>
__device__ __forceinline__ void scan_body(Sh& sh,
    const float* __restrict__ ts, const float* __restrict__ ys, const float* __restrict__ us,
    const float* __restrict__ x0g, const float* __restrict__ P0g, const float* __restrict__ Qg,
    float* __restrict__ out)
{
  const int tid = (int)threadIdx.x;
  const int wv = tid >> 6;        // wave 0..3, owns P rows 16wv..16wv+15
  const int l  = tid & 63;
  const int lc = l & 15, lg = l >> 4;
  const int xrow = tid >> 2, xpart = tid & 3;   // kx: 4 threads per x-row
  const int cq = tid >> 3, cpart = tid & 7;     // Cx: 8 threads per obs-row

  const float t0 = ts[0];
  const float h  = ts[1] - t0;
  f32x4 z4 = {0.f,0.f,0.f,0.f};
  f32x4 Pfr[4], Qfr[4], kP[6][4], APd[4], APT[4];
  s16x8 aA[2], bA[4][2], aRC[2][2], aC[2][2];
  float u0=0.f,u1=0.f,u2=0.f, y0=0.f,y1=0.f,y2=0.f;
  #pragma unroll
  for (int ct = 0; ct < 4; ++ct) { Pfr[ct]=z4; Qfr[ct]=z4; APd[ct]=z4; APT[ct]=z4; }
  #pragma unroll
  for (int j = 0; j < 6; ++j)
    #pragma unroll
    for (int ct = 0; ct < 4; ++ct) kP[j][ct] = z4;

  #pragma unroll
  for (int ct = 0; ct < 4; ++ct)
    #pragma unroll
    for (int r = 0; r < 4; ++r) {
      int row = 16*wv + 4*lg + r, col = 16*ct + lc;
      Pfr[ct][r] = P0g[row*64 + col];
      Qfr[ct][r] = Qg [row*64 + col];
    }
  aA[0] = load_fragT<HYP>(sh.Ab, PP, 16*wv, 0);
  aA[1] = load_fragT<HYP>(sh.Ab, PP, 16*wv, 32);
  #pragma unroll
  for (int ct = 0; ct < 4; ++ct)
    #pragma unroll
    for (int kb = 0; kb < 2; ++kb) bA[ct][kb] = load_fragT<HYP>(sh.Ab, PP, 16*ct, 32*kb);
  #pragma unroll
  for (int rt = 0; rt < 2; ++rt)
    #pragma unroll
    for (int kb = 0; kb < 2; ++kb) {
      aRC[rt][kb] = load_fragT<HYP>(sh.RCb, PP, 16*rt, 32*kb);
      aC [rt][kb] = load_fragT<HYP>(sh.Cb,  PP, 16*rt, 32*kb);
    }
  if (tid < 64) { float x0v = x0g[tid]; sh.XR[tid] = x0v; out[tid] = x0v; }
  u0 = us[tid & 15]; u1 = us[NI + (tid & 15)];
  y0 = ys[cq];       y1 = ys[NO + cq];
  __syncthreads();

  for (int t = 0; t < TN - 1; ++t) {
    const float tcur = ts[t];
    if (t + 2 < TN) { u2 = us[(t+2)*NI + (tid & 15)]; y2 = ys[(t+2)*NO + cq]; }
    #pragma unroll
    for (int st = 0; st < 6; ++st) {
      const int par = st & 1, prv = par ^ 1;
      // ======== PHASE A ========
      // ---- x-side: finish slope k[st-1], stage-combine xi, write XV/UV ----
      if (t > 0 || st > 0) {
        float kx;
        {
          const f32x4* xv4 = (const f32x4*)&sh.XV[prv][16*xpart];
          s16x8 a0 = *(const s16x8*)&sh.Ab[xrow*PP + 16*xpart];
          s16x8 a1 = *(const s16x8*)&sh.Ab[xrow*PP + 16*xpart + 8];
          kx = dot8(a0, xv4[0], xv4[1]) + dot8(a1, xv4[2], xv4[3]);
          f32x4 bv = *(const f32x4*)&sh.Bf[xrow*16 + 4*xpart];
          f32x4 uvv = *(const f32x4*)&sh.UV[prv][4*xpart];
          kx += bv.x*uvv.x + bv.y*uvv.y + bv.z*uvv.z + bv.w*uvv.w;
          s16x8 kkv = *(const s16x8*)&sh.KKb[xrow*PK + 8*xpart];
          const f32x4* cx4 = (const f32x4*)&sh.CXR[8*xpart];
          kx += dot8(kkv, cx4[0], cx4[1]);
        }
        kx += __shfl_xor(kx, 1);
        kx += __shfl_xor(kx, 2);
        const float xrold = sh.XR[xrow];
        float xi;
        if (st == 0) {
          float xn = xrold + h*(BW0*sh.kxs[0][xrow] + BW2*sh.kxs[2][xrow]
                              + BW3*sh.kxs[3][xrow] + BW4*sh.kxs[4][xrow] + BW5*kx);
          if (xpart == 0) { sh.XR[xrow] = xn; out[t*64 + xrow] = xn; }
          xi = xn;
        } else {
          if (xpart == 0) sh.kxs[st-1][xrow] = kx;
          xi = xrold;
          #pragma unroll
          for (int j = 0; j + 1 < st; ++j)
            if (ATAB[st][j] != 0.f) xi += (h * ATAB[st][j]) * sh.kxs[j][xrow];
          xi += (h * ATAB[st][st-1]) * kx;
        }
        if (xpart == 0) sh.XV[par][xrow] = xi;
      } else {
        if (xpart == 0) sh.XV[par][xrow] = sh.XR[xrow];
      }
      {
        int sel; float w;
        interp_iw(tcur, CTAB[st], t0, h, t, sel, w);
        if (tid < 16) {
          float ua = sel ? u1 : u0, ub = sel ? u2 : u1;
          sh.UV[par][tid] = ua * (1.f - w) + ub * w;
        }
      }
      // ---- P-side: M via MFMA, finish kP[st-1], stage combine, pack Pi ----
      if (t > 0 || st > 0) {
        const int ps = (st == 0) ? 5 : st - 1;
        s16x8 am = load_fragT<HYP>(sh.KKb, PK, 16*wv, 0);
        #pragma unroll
        for (int ct = 0; ct < 4; ++ct) {
          s16x8 bg = load_fragT<HYP>(sh.GTb, PK, 16*ct, 0);
          f32x4 M = MFT<HYP>(am, bg, z4);
          #pragma unroll
          for (int r = 0; r < 4; ++r)
            kP[ps][ct][r] = APd[ct][r] + APT[ct][r] - M[r];
        }
      }
      #pragma unroll
      for (int ct = 0; ct < 4; ++ct) {
        float v[4];
        #pragma unroll
        for (int r = 0; r < 4; ++r) {
          float x;
          if (st == 0) {
            if (t > 0)
              Pfr[ct][r] += h * (BW0*kP[0][ct][r] + BW2*kP[2][ct][r] + BW3*kP[3][ct][r]
                               + BW4*kP[4][ct][r] + BW5*kP[5][ct][r] + Qfr[ct][r]);
            x = Pfr[ct][r];
          } else {
            x = Pfr[ct][r] + (h * CTAB[st]) * Qfr[ct][r];
            #pragma unroll
            for (int j = 0; j < 5; ++j)
              if (ATAB[st][j] != 0.f) x += (h * ATAB[st][j]) * kP[j][ct][r];
          }
          v[r] = x;
        }
        uint2 pk; pk.x = pack2bf(v[0], v[1]); pk.y = pack2bf(v[2], v[3]);
        *(uint2*)&sh.Pib[(16*ct + lc)*PP + 16*wv + 4*lg] = pk;   // transpose-pack (Pi sym)
      }
      __syncthreads();
      // ======== PHASE B ========
      // ---- P-side: APd/APT + KK/GT strip ----
      {
        s16x8 aPi0 = load_fragT<HYP>(sh.Pib, PP, 16*wv, 0);
        s16x8 aPi1 = load_fragT<HYP>(sh.Pib, PP, 16*wv, 32);
        #pragma unroll
        for (int ct = 0; ct < 4; ++ct) {
          s16x8 bP0 = load_fragT<HYP>(sh.Pib, PP, 16*ct, 0);
          s16x8 bP1 = load_fragT<HYP>(sh.Pib, PP, 16*ct, 32);
          f32x4 acc = MFT<HYP>(aA[0], bP0, z4);
          APd[ct] = MFT<HYP>(aA[1], bP1, acc);
          f32x4 acc2 = MFT<HYP>(aPi0, bA[ct][0], z4);
          APT[ct] = MFT<HYP>(aPi1, bA[ct][1], acc2);
        }
        #pragma unroll
        for (int rt = 0; rt < 2; ++rt) {
          f32x4 aK = MFT<HYP>(aRC[rt][0], aPi0, z4);
          aK = MFT<HYP>(aRC[rt][1], aPi1, aK);
          uint2 pkk; pkk.x = pack2bf(aK[0], aK[1]); pkk.y = pack2bf(aK[2], aK[3]);
          *(uint2*)&sh.KKb[(16*wv + lc)*PK + 16*rt + 4*lg] = pkk;
          f32x4 aG = MFT<HYP>(aC[rt][0], aPi0, z4);
          aG = MFT<HYP>(aC[rt][1], aPi1, aG);
          uint2 pkg; pkg.x = pack2bf(aG[0], aG[1]); pkg.y = pack2bf(aG[2], aG[3]);
          *(uint2*)&sh.GTb[(16*wv + lc)*PK + 16*rt + 4*lg] = pkg;
        }
      }
      // ---- x-side: Cx = C@xi, CXR = y_interp - Cx ----
      {
        s16x8 cv = *(const s16x8*)&sh.Cb[cq*PP + 8*cpart];
        const f32x4* xv4 = (const f32x4*)&sh.XV[par][8*cpart];
        float cx = dot8(cv, xv4[0], xv4[1]);
        cx += __shfl_xor(cx, 1);
        cx += __shfl_xor(cx, 2);
        cx += __shfl_xor(cx, 4);
        int sel; float w;
        interp_iw(tcur, CTAB[st], t0, h, t, sel, w);
        if (cpart == 0) {
          float ya = sel ? y1 : y0, yb = sel ? y2 : y1;
          sh.CXR[cq] = (ya * (1.f - w) + yb * w) - cx;
        }
      }
      __syncthreads();
    } // stages
    u0 = u1; u1 = u2; y0 = y1; y1 = y2;
  } // t

  // tail: slope k5 of last step + final x combine
  {
    const int prv = 1;
    float kx;
    {
      const f32x4* xv4 = (const f32x4*)&sh.XV[prv][16*xpart];
      s16x8 a0 = *(const s16x8*)&sh.Ab[xrow*PP + 16*xpart];
      s16x8 a1 = *(const s16x8*)&sh.Ab[xrow*PP + 16*xpart + 8];
      kx = dot8(a0, xv4[0], xv4[1]) + dot8(a1, xv4[2], xv4[3]);
      f32x4 bv = *(const f32x4*)&sh.Bf[xrow*16 + 4*xpart];
      f32x4 uvv = *(const f32x4*)&sh.UV[prv][4*xpart];
      kx += bv.x*uvv.x + bv.y*uvv.y + bv.z*uvv.z + bv.w*uvv.w;
      s16x8 kkv = *(const s16x8*)&sh.KKb[xrow*PK + 8*xpart];
      const f32x4* cx4 = (const f32x4*)&sh.CXR[8*xpart];
      kx += dot8(kkv, cx4[0], cx4[1]);
    }
    kx += __shfl_xor(kx, 1);
    kx += __shfl_xor(kx, 2);
    if (xpart == 0) {
      float xn = sh.XR[xrow] + h*(BW0*sh.kxs[0][xrow] + BW2*sh.kxs[2][xrow]
                                + BW3*sh.kxs[3][xrow] + BW4*sh.kxs[4][xrow] + BW5*kx);
      out[(TN - 1)*64 + xrow] = xn;
    }
  }
}

__global__ __launch_bounds__(256, 1)
void kf_mfma5(const float* __restrict__ ts, const float* __restrict__ ys,
              const float* __restrict__ us, const float* __restrict__ Ag,
              const float* __restrict__ Bg, const float* __restrict__ Cg,
              const float* __restrict__ x0g, const float* __restrict__ P0g,
              const float* __restrict__ Qg, const float* __restrict__ Rg,
              float* __restrict__ out)
{
  __shared__ Sh sh;
  const int tid = (int)threadIdx.x;
  const int wv = tid >> 6;
  const int lc = tid & 15, lg = (tid & 63) >> 4;

  // ===================== init =====================
  for (int idx = tid; idx < 64*64; idx += 256) sh.Ab[(idx>>6)*PP + (idx&63)] = f2bf(Ag[idx]);
  for (int idx = tid; idx < 32*64; idx += 256) sh.Cb[(idx>>6)*PP + (idx&63)] = f2bf(Cg[idx]);
  for (int idx = tid; idx < 64*16; idx += 256) sh.Bf[idx] = Bg[idx];
  for (int idx = tid; idx < 32*64; idx += 256) {
    int r = idx >> 6, c = idx & 63;
    sh.GJ[idx] = (c < 32) ? Rg[r*32 + c] : ((c - 32) == r ? 1.f : 0.f);
  }
  __syncthreads();
  for (int k2 = 0; k2 < 32; ++k2) {
    if (tid < 32) sh.FAC[tid] = sh.GJ[tid*64 + k2];
    __syncthreads();
    const float pinv = 1.f / sh.FAC[k2];
    float oldv[8], vk[8];
    #pragma unroll
    for (int s = 0; s < 8; ++s) {
      int idx = tid + s*256;
      oldv[s] = sh.GJ[idx];
      vk[s]   = sh.GJ[k2*64 + (idx & 63)];
    }
    __syncthreads();
    #pragma unroll
    for (int s = 0; s < 8; ++s) {
      int idx = tid + s*256, i = idx >> 6;
      sh.GJ[idx] = (i == k2) ? (oldv[s] * pinv) : (oldv[s] - sh.FAC[i] * (vk[s] * pinv));
    }
    __syncthreads();
  }
  for (int idx = tid; idx < 32*64; idx += 256) {   // RC = Rinv @ C
    int q = idx >> 6, k = idx & 63;
    float a = 0.f;
    for (int p = 0; p < 32; ++p) a += sh.GJ[q*64 + 32 + p] * Cg[p*64 + k];
    sh.RCb[q*PP + k] = f2bf(a);
  }
  __syncthreads();
  // fragment-layout reference: X[r][c] = sum_{k<32} A[r][k]*A[16+c][k]  (asymmetric, swap-detecting)
  if (tid < 256) {
    int r = tid >> 4, c = tid & 15;
    float a = 0.f;
    for (int k = 0; k < 32; ++k) a += bf2f(sh.Ab[r*PP + k]) * bf2f(sh.Ab[(16 + c)*PP + k]);
    sh.GJ[tid] = a;
  }
  if (tid == 0) sh.HYP = -1;
  __syncthreads();
  for (int hh = 0; hh < 4; ++hh) {
    if (wv == 0) {
      s16x8 af = load_frag(sh.Ab, PP, 0, 0, hh);
      s16x8 bf = load_frag(sh.Ab, PP, 16, 0, hh);
      f32x4 z = {0.f,0.f,0.f,0.f};
      f32x4 d = MF(af, bf, z, hh);
      int ok = 1;
      #pragma unroll
      for (int r = 0; r < 4; ++r) {
        float rf = sh.GJ[(lg*4 + r)*16 + lc];
        ok &= (fabsf(d[r] - rf) <= 1e-3f + 1e-2f * fabsf(rf)) ? 1 : 0;
      }
      if (__all(ok) && tid == 0) { if (sh.HYP < 0) sh.HYP = hh; }
    }
    __syncthreads();
  }
  const int sHyp = (sh.HYP < 0) ? 0 : sh.HYP;

  switch (sHyp) {
    case 0: scan_body<0>(sh, ts, ys, us, x0g, P0g, Qg, out); break;
    case 1: scan_body<1>(sh, ts, ys, us, x0g, P0g, Qg, out); break;
    case 2: scan_body<2>(sh, ts, ys, us, x0g, P0g, Qg, out); break;
    default: scan_body<3>(sh, ts, ys, us, x0g, P0g, Qg, out); break;
  }
}

extern "C" void kernel_launch(void* const* d_in, const int* in_sizes, int n_in,
                              void* d_out, int out_size, void* d_ws, size_t ws_size,
                              hipStream_t stream) {
  (void)in_sizes; (void)n_in; (void)out_size; (void)d_ws; (void)ws_size;
  const float* ts  = (const float*)d_in[0];
  const float* ys  = (const float*)d_in[1];
  const float* us  = (const float*)d_in[2];
  const float* A   = (const float*)d_in[3];
  const float* B   = (const float*)d_in[4];
  const float* C   = (const float*)d_in[5];
  const float* x0  = (const float*)d_in[6];
  const float* P0  = (const float*)d_in[7];
  const float* Q   = (const float*)d_in[8];
  const float* R   = (const float*)d_in[9];
  hipLaunchKernelGGL(kf_mfma5, dim3(1), dim3(256), 0, stream,
                     ts, ys, us, A, B, C, x0, P0, Q, R, (float*)d_out);
}

// Round 9
// 8896.575 us; speedup vs baseline: 2.5596x; 1.3648x over previous
//
#include <hip/hip_runtime.h>

typedef float f32x4 __attribute__((ext_vector_type(4)));
typedef short s16x8 __attribute__((ext_vector_type(8)));
typedef short s16x4 __attribute__((ext_vector_type(4)));

namespace kf {
constexpr int TN = 1024, NS = 64, NO = 32, NI = 16;
constexpr int PP = 72;   // u16 pitch, 64-col bf16 arrays
constexpr int PK = 40;   // u16 pitch, 32-col bf16 arrays
constexpr int PKP = 72;  // f32 pitch (row dim) for kP slope store

constexpr float ATAB[6][5] = {
  {0.f,0.f,0.f,0.f,0.f},
  {(float)(1.0/5.0),0.f,0.f,0.f,0.f},
  {(float)(3.0/40.0),(float)(9.0/40.0),0.f,0.f,0.f},
  {(float)(44.0/45.0),(float)(-56.0/15.0),(float)(32.0/9.0),0.f,0.f},
  {(float)(19372.0/6561.0),(float)(-25360.0/2187.0),(float)(64448.0/6561.0),(float)(-212.0/729.0),0.f},
  {(float)(9017.0/3168.0),(float)(-355.0/33.0),(float)(46732.0/5247.0),(float)(49.0/176.0),(float)(-5103.0/18656.0)},
};
constexpr float CTAB[6] = {0.f,(float)(1.0/5.0),(float)(3.0/10.0),(float)(4.0/5.0),(float)(8.0/9.0),1.f};
constexpr float BW0=(float)(35.0/384.0), BW2=(float)(500.0/1113.0), BW3=(float)(125.0/192.0),
                BW4=(float)(-2187.0/6784.0), BW5=(float)(11.0/84.0);

struct ShB {
  unsigned short Pib[64*PP];
  unsigned short Ab [64*PP];
  unsigned short Cb [32*PP];
  unsigned short RCb[32*PP];
  unsigned short KKb[64*PK];
  unsigned short GTb[64*PK];
  float Bf[64*16];
  float XV[2][64];
  float CXR[32];
  float BUB[2][64];
  float FAC[32];
  int HYP;
};
constexpr size_t SH_BASE  = (sizeof(ShB) + 255) & ~size_t(255);
constexpr size_t SH_TOTAL = SH_BASE + size_t(5*64*PKP)*4;
} // namespace kf
using namespace kf;

__device__ inline float bf2f(unsigned short u){
  unsigned int x = ((unsigned int)u) << 16; return __builtin_bit_cast(float, x);
}
__device__ inline unsigned short f2bf(float f){
  unsigned int x = __builtin_bit_cast(unsigned int, f);
  return (unsigned short)((x + 0x7fffu + ((x >> 16) & 1u)) >> 16);
}
__device__ inline unsigned int pack2bf(float a, float b){
  return (unsigned int)f2bf(a) | ((unsigned int)f2bf(b) << 16);
}
__device__ inline s16x8 load_frag(const unsigned short* arr, int pitch, int row0, int k0, int hyp){
  const int l = (int)(threadIdx.x & 63), lc = l & 15, lg = l >> 4;
  const unsigned short* p = arr + (row0 + lc) * pitch + k0;
  if ((hyp & 1) == 0) {
    return *(const s16x8*)(p + lg * 8);
  } else {
    s16x4 a = *(const s16x4*)(p + lg * 4);
    s16x4 b = *(const s16x4*)(p + 16 + lg * 4);
    s16x8 r; r[0]=a[0]; r[1]=a[1]; r[2]=a[2]; r[3]=a[3]; r[4]=b[0]; r[5]=b[1]; r[6]=b[2]; r[7]=b[3];
    return r;
  }
}
__device__ inline f32x4 MF(s16x8 a, s16x8 b, f32x4 c, int hyp){
  if (hyp & 2) return __builtin_amdgcn_mfma_f32_16x16x32_bf16(b, a, c, 0, 0, 0);
  return __builtin_amdgcn_mfma_f32_16x16x32_bf16(a, b, c, 0, 0, 0);
}
template<int HYP>
__device__ __forceinline__ s16x8 load_fragT(const unsigned short* arr, int pitch, int row0, int k0){
  const int l = (int)(threadIdx.x & 63), lc = l & 15, lg = l >> 4;
  const unsigned short* p = arr + (row0 + lc) * pitch + k0;
  if constexpr ((HYP & 1) == 0) {
    return *(const s16x8*)(p + lg * 8);
  } else {
    s16x4 a = *(const s16x4*)(p + lg * 4);
    s16x4 b = *(const s16x4*)(p + 16 + lg * 4);
    s16x8 r; r[0]=a[0]; r[1]=a[1]; r[2]=a[2]; r[3]=a[3]; r[4]=b[0]; r[5]=b[1]; r[6]=b[2]; r[7]=b[3];
    return r;
  }
}
template<int HYP>
__device__ __forceinline__ f32x4 MFT(s16x8 a, s16x8 b, f32x4 c){
  if constexpr ((HYP & 2) != 0) return __builtin_amdgcn_mfma_f32_16x16x32_bf16(b, a, c, 0, 0, 0);
  else                          return __builtin_amdgcn_mfma_f32_16x16x32_bf16(a, b, c, 0, 0, 0);
}
__device__ inline float dot8(s16x8 v, f32x4 a, f32x4 b){
  return bf2f(v[0])*a.x + bf2f(v[1])*a.y + bf2f(v[2])*a.z + bf2f(v[3])*a.w
       + bf2f(v[4])*b.x + bf2f(v[5])*b.y + bf2f(v[6])*b.z + bf2f(v[7])*b.w;
}
__device__ inline float dot4bf(s16x4 v, f32x4 a){
  return bf2f(v[0])*a.x + bf2f(v[1])*a.y + bf2f(v[2])*a.z + bf2f(v[3])*a.w;
}

template<int HYP>
__device__ __forceinline__ void scan_body(ShB& sh, float* __restrict__ KPL,
    const float* __restrict__ ts, const float* __restrict__ ys, const float* __restrict__ us,
    const float* __restrict__ x0g, const float* __restrict__ P0g, const float* __restrict__ Qg,
    float* __restrict__ out)
{
  const int tid = (int)threadIdx.x;
  const int w = tid >> 6, l = tid & 63;
  const int lc = l & 15, lg = l >> 4;
  const int sr = w & 3, ch = w >> 2;
  const int xrow = tid >> 3, xpart = tid & 7;
  const int cq = tid >> 4, cpart = tid & 15;

  const float h = ts[1] - ts[0];
  f32x4 z4 = {0.f,0.f,0.f,0.f};
  f32x4 Pfr[2], Qfr[2], APd[2], APT[2];
  s16x8 aA[2], aRC[2], aC[2];
  float XRr, kx0=0.f,kx1=0.f,kx2=0.f,kx3=0.f,kx4=0.f;
  float y1, y2;
  #pragma unroll
  for (int c2 = 0; c2 < 2; ++c2) { Pfr[c2]=z4; Qfr[c2]=z4; APd[c2]=z4; APT[c2]=z4; }

  #pragma unroll
  for (int c2 = 0; c2 < 2; ++c2)
    #pragma unroll
    for (int r = 0; r < 4; ++r) {
      int row = 16*sr + 4*lg + r, col = 16*(2*ch + c2) + lc;
      Pfr[c2][r] = P0g[row*64 + col];
      Qfr[c2][r] = Qg [row*64 + col];
    }
  #pragma unroll
  for (int kb = 0; kb < 2; ++kb) {
    aA [kb] = load_fragT<HYP>(sh.Ab,  PP, 16*sr, 32*kb);
    aRC[kb] = load_fragT<HYP>(sh.RCb, PP, 16*ch, 32*kb);
    aC [kb] = load_fragT<HYP>(sh.Cb,  PP, 16*ch, 32*kb);
  }
  XRr = x0g[xrow];
  if (tid < 64) {
    out[tid] = x0g[tid];
    const f32x4* bf4 = (const f32x4*)&sh.Bf[tid*16];
    const f32x4* up4 = (const f32x4*)us;
    float bu = 0.f;
    #pragma unroll
    for (int m4 = 0; m4 < 4; ++m4) {
      f32x4 b = bf4[m4], u = up4[m4];
      bu += b.x*u.x + b.y*u.y + b.z*u.z + b.w*u.w;
    }
    sh.BUB[0][tid] = bu;
  }
  y1 = ys[cq]; y2 = ys[NO + cq];
  __syncthreads();

  for (int t = 0; t < TN - 1; ++t) {
    #pragma unroll
    for (int st = 0; st < 6; ++st) {
      const int par = st & 1, prv = par ^ 1;
      // ================= PHASE A =================
      if (t > 0 || st > 0) {
        float kx;
        {
          s16x8 a0 = *(const s16x8*)&sh.Ab[xrow*PP + 8*xpart];
          f32x4 xa = *(const f32x4*)&sh.XV[prv][8*xpart];
          f32x4 xb = *(const f32x4*)&sh.XV[prv][8*xpart + 4];
          kx = dot8(a0, xa, xb);
          s16x4 kkv = *(const s16x4*)&sh.KKb[xrow*PK + 4*xpart];
          f32x4 cxv = *(const f32x4*)&sh.CXR[4*xpart];
          kx += dot4bf(kkv, cxv);
        }
        kx += __shfl_xor(kx, 1);
        kx += __shfl_xor(kx, 2);
        kx += __shfl_xor(kx, 4);
        // R6/R7 BUG: BUB (full per-row value) was added BEFORE the 8-lane
        // butterfly -> counted 8x. Add it AFTER the reduce (uniform per group).
        if (st == 0) {
          kx += sh.BUB[t & 1][xrow];
        } else {
          const float cp = CTAB[st-1];
          kx += (1.f - cp) * sh.BUB[t & 1][xrow] + cp * sh.BUB[(t + 1) & 1][xrow];
        }
        if (st == 0) {
          float xn = XRr + h*(BW0*kx0 + BW2*kx2 + BW3*kx3 + BW4*kx4 + BW5*kx);
          XRr = xn;
          if (xpart == 0) { out[t*64 + xrow] = xn; sh.XV[par][xrow] = xn; }
        } else {
          float xi = XRr + (h * ATAB[st][st-1]) * kx;
          if (st >= 2 && ATAB[st][0] != 0.f) xi += (h * ATAB[st][0]) * kx0;
          if (st >= 3 && ATAB[st][1] != 0.f) xi += (h * ATAB[st][1]) * kx1;
          if (st >= 4 && ATAB[st][2] != 0.f) xi += (h * ATAB[st][2]) * kx2;
          if (st >= 5 && ATAB[st][3] != 0.f) xi += (h * ATAB[st][3]) * kx3;
          if (st == 1) kx0 = kx; else if (st == 2) kx1 = kx;
          else if (st == 3) kx2 = kx; else if (st == 4) kx3 = kx; else kx4 = kx;
          if (xpart == 0) sh.XV[par][xrow] = xi;
        }
      } else {
        if (xpart == 0) sh.XV[0][xrow] = XRr;
      }
      if (t > 0 || st > 0) {
        s16x8 am = load_fragT<HYP>(sh.KKb, PK, 16*sr, 0);
        #pragma unroll
        for (int c2 = 0; c2 < 2; ++c2) {
          const int ct = 2*ch + c2;
          s16x8 bg = load_fragT<HYP>(sh.GTb, PK, 16*ct, 0);
          f32x4 M = MFT<HYP>(am, bg, z4);
          f32x4 kPv;
          #pragma unroll
          for (int r = 0; r < 4; ++r) kPv[r] = APd[c2][r] + APT[c2][r] - M[r];
          float* kbase = &KPL[(size_t)(16*ct + lc) * PKP + 16*sr + 4*lg];
          f32x4 x;
          if (st == 0) {
            f32x4 k0v = *(const f32x4*)(kbase + 0*64*PKP);
            f32x4 k2v = *(const f32x4*)(kbase + 2*64*PKP);
            f32x4 k3v = *(const f32x4*)(kbase + 3*64*PKP);
            f32x4 k4v = *(const f32x4*)(kbase + 4*64*PKP);
            #pragma unroll
            for (int r = 0; r < 4; ++r)
              Pfr[c2][r] += h * (BW0*k0v[r] + BW2*k2v[r] + BW3*k3v[r]
                               + BW4*k4v[r] + BW5*kPv[r] + Qfr[c2][r]);
            x = Pfr[c2];
          } else {
            *(f32x4*)(kbase + (size_t)(st-1)*64*PKP) = kPv;
            #pragma unroll
            for (int r = 0; r < 4; ++r)
              x[r] = Pfr[c2][r] + (h * CTAB[st]) * Qfr[c2][r] + (h * ATAB[st][st-1]) * kPv[r];
            if (st >= 2) { f32x4 kv = *(const f32x4*)(kbase + 0*64*PKP);
              #pragma unroll
              for (int r = 0; r < 4; ++r) x[r] += (h * ATAB[st][0]) * kv[r]; }
            if (st >= 3) { f32x4 kv = *(const f32x4*)(kbase + 1*64*PKP);
              #pragma unroll
              for (int r = 0; r < 4; ++r) x[r] += (h * ATAB[st][1]) * kv[r]; }
            if (st >= 4) { f32x4 kv = *(const f32x4*)(kbase + 2*64*PKP);
              #pragma unroll
              for (int r = 0; r < 4; ++r) x[r] += (h * ATAB[st][2]) * kv[r]; }
            if (st >= 5) { f32x4 kv = *(const f32x4*)(kbase + 3*64*PKP);
              #pragma unroll
              for (int r = 0; r < 4; ++r) x[r] += (h * ATAB[st][3]) * kv[r]; }
          }
          uint2 pk; pk.x = pack2bf(x[0], x[1]); pk.y = pack2bf(x[2], x[3]);
          *(uint2*)&sh.Pib[(16*ct + lc)*PP + 16*sr + 4*lg] = pk;
        }
      } else {
        #pragma unroll
        for (int c2 = 0; c2 < 2; ++c2) {
          const int ct = 2*ch + c2;
          uint2 pk; pk.x = pack2bf(Pfr[c2][0], Pfr[c2][1]); pk.y = pack2bf(Pfr[c2][2], Pfr[c2][3]);
          *(uint2*)&sh.Pib[(16*ct + lc)*PP + 16*sr + 4*lg] = pk;
        }
      }
      __syncthreads();
      // ================= PHASE B =================
      {
        s16x8 aPi0 = load_fragT<HYP>(sh.Pib, PP, 16*sr, 0);
        s16x8 aPi1 = load_fragT<HYP>(sh.Pib, PP, 16*sr, 32);
        #pragma unroll
        for (int c2 = 0; c2 < 2; ++c2) {
          const int ct = 2*ch + c2;
          s16x8 bP0 = load_fragT<HYP>(sh.Pib, PP, 16*ct, 0);
          s16x8 bP1 = load_fragT<HYP>(sh.Pib, PP, 16*ct, 32);
          s16x8 bA0 = load_fragT<HYP>(sh.Ab,  PP, 16*ct, 0);
          s16x8 bA1 = load_fragT<HYP>(sh.Ab,  PP, 16*ct, 32);
          APd[c2] = MFT<HYP>(aA[1], bP1, MFT<HYP>(aA[0], bP0, z4));
          APT[c2] = MFT<HYP>(aPi1, bA1, MFT<HYP>(aPi0, bA0, z4));
        }
        f32x4 aK = MFT<HYP>(aRC[1], aPi1, MFT<HYP>(aRC[0], aPi0, z4));
        uint2 pkk; pkk.x = pack2bf(aK[0], aK[1]); pkk.y = pack2bf(aK[2], aK[3]);
        *(uint2*)&sh.KKb[(16*sr + lc)*PK + 16*ch + 4*lg] = pkk;
        f32x4 aG = MFT<HYP>(aC[1], aPi1, MFT<HYP>(aC[0], aPi0, z4));
        uint2 pkg; pkg.x = pack2bf(aG[0], aG[1]); pkg.y = pack2bf(aG[2], aG[3]);
        *(uint2*)&sh.GTb[(16*sr + lc)*PK + 16*ch + 4*lg] = pkg;
      }
      {
        s16x4 cvv = *(const s16x4*)&sh.Cb[cq*PP + 4*cpart];
        f32x4 xv = *(const f32x4*)&sh.XV[par][4*cpart];
        float cx = dot4bf(cvv, xv);
        cx += __shfl_xor(cx, 1);
        cx += __shfl_xor(cx, 2);
        cx += __shfl_xor(cx, 4);
        cx += __shfl_xor(cx, 8);
        if (cpart == 0) {
          float yc = (1.f - CTAB[st]) * y1 + CTAB[st] * y2;
          sh.CXR[cq] = yc - cx;
        }
      }
      if (st == 0 && tid < 64) {
        const f32x4* bf4 = (const f32x4*)&sh.Bf[tid*16];
        const f32x4* up4 = (const f32x4*)(us + (size_t)(t + 1)*NI);
        float bu = 0.f;
        #pragma unroll
        for (int m4 = 0; m4 < 4; ++m4) {
          f32x4 b = bf4[m4], u = up4[m4];
          bu += b.x*u.x + b.y*u.y + b.z*u.z + b.w*u.w;
        }
        sh.BUB[(t + 1) & 1][tid] = bu;
      }
      __syncthreads();
    } // stages
    y1 = y2;
    if (t + 2 < TN) y2 = ys[(size_t)(t + 2)*NO + cq];
  } // t

  // tail: slope 5 of last step + final x combine
  {
    constexpr int tb = (TN - 1) & 1;
    float kx;
    {
      s16x8 a0 = *(const s16x8*)&sh.Ab[xrow*PP + 8*xpart];
      f32x4 xa = *(const f32x4*)&sh.XV[1][8*xpart];
      f32x4 xb = *(const f32x4*)&sh.XV[1][8*xpart + 4];
      kx = dot8(a0, xa, xb);
      s16x4 kkv = *(const s16x4*)&sh.KKb[xrow*PK + 4*xpart];
      f32x4 cxv = *(const f32x4*)&sh.CXR[4*xpart];
      kx += dot4bf(kkv, cxv);
    }
    kx += __shfl_xor(kx, 1);
    kx += __shfl_xor(kx, 2);
    kx += __shfl_xor(kx, 4);
    kx += sh.BUB[tb][xrow];   // after reduce (was 8x-counted before)
    if (xpart == 0) {
      float xn = XRr + h*(BW0*kx0 + BW2*kx2 + BW3*kx3 + BW4*kx4 + BW5*kx);
      out[(TN - 1)*64 + xrow] = xn;
    }
  }
}

__global__ __launch_bounds__(512, 1)
void kf_mfma8(const float* __restrict__ ts, const float* __restrict__ ys,
              const float* __restrict__ us, const float* __restrict__ Ag,
              const float* __restrict__ Bg, const float* __restrict__ Cg,
              const float* __restrict__ x0g, const float* __restrict__ P0g,
              const float* __restrict__ Qg, const float* __restrict__ Rg,
              float* __restrict__ out)
{
  extern __shared__ char dsm[];
  ShB& sh = *(ShB*)dsm;
  float* KPL = (float*)(dsm + SH_BASE);
  float* GJ  = KPL;
  const int tid = (int)threadIdx.x;
  const int wv = tid >> 6;
  const int lc = tid & 15, lg = (tid & 63) >> 4;

  for (int idx = tid; idx < 64*64; idx += 512) sh.Ab[(idx>>6)*PP + (idx&63)] = f2bf(Ag[idx]);
  for (int idx = tid; idx < 32*64; idx += 512) sh.Cb[(idx>>6)*PP + (idx&63)] = f2bf(Cg[idx]);
  for (int idx = tid; idx < 64*16; idx += 512) sh.Bf[idx] = Bg[idx];
  for (int idx = tid; idx < 32*64; idx += 512) {
    int r = idx >> 6, c = idx & 63;
    GJ[idx] = (c < 32) ? Rg[r*32 + c] : ((c - 32) == r ? 1.f : 0.f);
  }
  __syncthreads();
  for (int k2 = 0; k2 < 32; ++k2) {
    if (tid < 32) sh.FAC[tid] = GJ[tid*64 + k2];
    __syncthreads();
    const float pinv = 1.f / sh.FAC[k2];
    float oldv[4], vk[4];
    #pragma unroll
    for (int s = 0; s < 4; ++s) {
      int idx = tid + s*512;
      oldv[s] = GJ[idx];
      vk[s]   = GJ[k2*64 + (idx & 63)];
    }
    __syncthreads();
    #pragma unroll
    for (int s = 0; s < 4; ++s) {
      int idx = tid + s*512, i = idx >> 6;
      GJ[idx] = (i == k2) ? (oldv[s] * pinv) : (oldv[s] - sh.FAC[i] * (vk[s] * pinv));
    }
    __syncthreads();
  }
  for (int idx = tid; idx < 32*64; idx += 512) {
    int q = idx >> 6, k = idx & 63;
    float a = 0.f;
    for (int p = 0; p < 32; ++p) a += GJ[q*64 + 32 + p] * Cg[p*64 + k];
    sh.RCb[q*PP + k] = f2bf(a);
  }
  __syncthreads();
  __shared__ float Xref[256];
  if (tid < 256) {
    int r = tid >> 4, c = tid & 15;
    float a = 0.f;
    for (int k = 0; k < 32; ++k) a += bf2f(sh.Ab[r*PP + k]) * bf2f(sh.Ab[(16 + c)*PP + k]);
    Xref[tid] = a;
  }
  if (tid == 0) sh.HYP = -1;
  __syncthreads();
  for (int hh = 0; hh < 4; ++hh) {
    if (wv == 0) {
      s16x8 af = load_frag(sh.Ab, PP, 0, 0, hh);
      s16x8 bf = load_frag(sh.Ab, PP, 16, 0, hh);
      f32x4 z = {0.f,0.f,0.f,0.f};
      f32x4 d = MF(af, bf, z, hh);
      int ok = 1;
      #pragma unroll
      for (int r = 0; r < 4; ++r) {
        float rf = Xref[(lg*4 + r)*16 + lc];
        ok &= (fabsf(d[r] - rf) <= 1e-3f + 1e-2f * fabsf(rf)) ? 1 : 0;
      }
      if (__all(ok) && tid == 0) { if (sh.HYP < 0) sh.HYP = hh; }
    }
    __syncthreads();
  }
  const int sHyp = (sh.HYP < 0) ? 0 : sh.HYP;

  switch (sHyp) {
    case 0: scan_body<0>(sh, KPL, ts, ys, us, x0g, P0g, Qg, out); break;
    case 1: scan_body<1>(sh, KPL, ts, ys, us, x0g, P0g, Qg, out); break;
    case 2: scan_body<2>(sh, KPL, ts, ys, us, x0g, P0g, Qg, out); break;
    default: scan_body<3>(sh, KPL, ts, ys, us, x0g, P0g, Qg, out); break;
  }
}

extern "C" void kernel_launch(void* const* d_in, const int* in_sizes, int n_in,
                              void* d_out, int out_size, void* d_ws, size_t ws_size,
                              hipStream_t stream) {
  (void)in_sizes; (void)n_in; (void)out_size; (void)d_ws; (void)ws_size;
  const float* ts  = (const float*)d_in[0];
  const float* ys  = (const float*)d_in[1];
  const float* us  = (const float*)d_in[2];
  const float* A   = (const float*)d_in[3];
  const float* B   = (const float*)d_in[4];
  const float* C   = (const float*)d_in[5];
  const float* x0  = (const float*)d_in[6];
  const float* P0  = (const float*)d_in[7];
  const float* Q   = (const float*)d_in[8];
  const float* R   = (const float*)d_in[9];
  (void)hipFuncSetAttribute(reinterpret_cast<const void*>(kf_mfma8),
                            hipFuncAttributeMaxDynamicSharedMemorySize, (int)SH_TOTAL);
  hipLaunchKernelGGL(kf_mfma8, dim3(1), dim3(512), SH_TOTAL, stream,
                     ts, ys, us, A, B, C, x0, P0, Q, R, (float*)d_out);
}

// Round 10
// 7367.233 us; speedup vs baseline: 3.0909x; 1.2076x over previous
//
#include <hip/hip_runtime.h>

typedef float f32x4 __attribute__((ext_vector_type(4)));
typedef short s16x8 __attribute__((ext_vector_type(8)));
typedef short s16x4 __attribute__((ext_vector_type(4)));

namespace kf {
constexpr int TN = 1024, NS = 64, NO = 32, NI = 16;
constexpr int PP = 72;   // u16 pitch, 64-col bf16 arrays
constexpr int PK = 40;   // u16 pitch, 32-col bf16 arrays
constexpr int PKP = 72;  // f32 pitch for kP slope store

constexpr float ATAB[6][5] = {
  {0.f,0.f,0.f,0.f,0.f},
  {(float)(1.0/5.0),0.f,0.f,0.f,0.f},
  {(float)(3.0/40.0),(float)(9.0/40.0),0.f,0.f,0.f},
  {(float)(44.0/45.0),(float)(-56.0/15.0),(float)(32.0/9.0),0.f,0.f},
  {(float)(19372.0/6561.0),(float)(-25360.0/2187.0),(float)(64448.0/6561.0),(float)(-212.0/729.0),0.f},
  {(float)(9017.0/3168.0),(float)(-355.0/33.0),(float)(46732.0/5247.0),(float)(49.0/176.0),(float)(-5103.0/18656.0)},
};
constexpr float CTAB[6] = {0.f,(float)(1.0/5.0),(float)(3.0/10.0),(float)(4.0/5.0),(float)(8.0/9.0),1.f};
constexpr float BW0=(float)(35.0/384.0), BW2=(float)(500.0/1113.0), BW3=(float)(125.0/192.0),
                BW4=(float)(-2187.0/6784.0), BW5=(float)(11.0/84.0);

struct ShB {
  unsigned short Pib[80*PP];   // Pi augmented: row 64 = xi (bf16), rows 65-79 = 0
  unsigned short Ab [64*PP];
  unsigned short Cb [32*PP];
  unsigned short RCb[32*PP];
  unsigned short KKb[64*PK];
  unsigned short GTb[80*PK];   // GT augmented: row 64 = cxr = y_c - C@xi, rows 65-79 = 0
  float Bf[64*16];
  float BUB[2][64];            // B@u[t] ping-pong
  float KXL[5][64];            // x slopes k0..k4
  float FAC[32];
  int HYP;
};
constexpr size_t SH_BASE  = (sizeof(ShB) + 255) & ~size_t(255);
constexpr size_t SH_TOTAL = SH_BASE + size_t(5*64*PKP)*4;
} // namespace kf
using namespace kf;

__device__ inline float bf2f(unsigned short u){
  unsigned int x = ((unsigned int)u) << 16; return __builtin_bit_cast(float, x);
}
__device__ inline unsigned short f2bf(float f){
  unsigned int x = __builtin_bit_cast(unsigned int, f);
  return (unsigned short)((x + 0x7fffu + ((x >> 16) & 1u)) >> 16);
}
__device__ inline unsigned int pack2bf(float a, float b){
  return (unsigned int)f2bf(a) | ((unsigned int)f2bf(b) << 16);
}
__device__ inline s16x8 load_frag(const unsigned short* arr, int pitch, int row0, int k0, int hyp){
  const int l = (int)(threadIdx.x & 63), lc = l & 15, lg = l >> 4;
  const unsigned short* p = arr + (row0 + lc) * pitch + k0;
  if ((hyp & 1) == 0) {
    return *(const s16x8*)(p + lg * 8);
  } else {
    s16x4 a = *(const s16x4*)(p + lg * 4);
    s16x4 b = *(const s16x4*)(p + 16 + lg * 4);
    s16x8 r; r[0]=a[0]; r[1]=a[1]; r[2]=a[2]; r[3]=a[3]; r[4]=b[0]; r[5]=b[1]; r[6]=b[2]; r[7]=b[3];
    return r;
  }
}
__device__ inline f32x4 MF(s16x8 a, s16x8 b, f32x4 c, int hyp){
  if (hyp & 2) return __builtin_amdgcn_mfma_f32_16x16x32_bf16(b, a, c, 0, 0, 0);
  return __builtin_amdgcn_mfma_f32_16x16x32_bf16(a, b, c, 0, 0, 0);
}
template<int HYP>
__device__ __forceinline__ s16x8 load_fragT(const unsigned short* arr, int pitch, int row0, int k0){
  const int l = (int)(threadIdx.x & 63), lc = l & 15, lg = l >> 4;
  const unsigned short* p = arr + (row0 + lc) * pitch + k0;
  if constexpr ((HYP & 1) == 0) {
    return *(const s16x8*)(p + lg * 8);
  } else {
    s16x4 a = *(const s16x4*)(p + lg * 4);
    s16x4 b = *(const s16x4*)(p + 16 + lg * 4);
    s16x8 r; r[0]=a[0]; r[1]=a[1]; r[2]=a[2]; r[3]=a[3]; r[4]=b[0]; r[5]=b[1]; r[6]=b[2]; r[7]=b[3];
    return r;
  }
}
template<int HYP>
__device__ __forceinline__ f32x4 MFT(s16x8 a, s16x8 b, f32x4 c){
  if constexpr ((HYP & 2) != 0) return __builtin_amdgcn_mfma_f32_16x16x32_bf16(b, a, c, 0, 0, 0);
  else                          return __builtin_amdgcn_mfma_f32_16x16x32_bf16(a, b, c, 0, 0, 0);
}

// Augmented-state design: Pib row 64 carries xi. Then (verified D layout:
// row = first operand tile 4*lg+r, col = second operand tile lc):
//   APdX = A-frag x PibX-frag  -> col lc==0 = A@xi          (ch0 waves)
//   GTX  = C-frag x PibX-frag  -> Cxi; fixed up to cxr,
//          masked store: rows 65-79 stay 0                   (sr3 waves)
//   MX   = KK-frag x GTX-frag  -> col lc==0 = K@cxr          (ch0 waves)
// kx = APdX + MX + Bu in lanes lc==0 (f32x4 of 4 state rows). Junk lanes
// read zero rows -> exact 0, no NaN contamination.
template<int HYP>
__device__ __forceinline__ void scan_body(ShB& sh, float* __restrict__ KPL,
    const float* __restrict__ ts, const float* __restrict__ ys, const float* __restrict__ us,
    const float* __restrict__ x0g, const float* __restrict__ P0g, const float* __restrict__ Qg,
    float* __restrict__ out)
{
  const int tid = (int)threadIdx.x;
  const int w = tid >> 6, l = tid & 63;
  const int lc = l & 15, lg = l >> 4;
  const int sr = w & 3, ch = w >> 2;
  const int rowbase = 16*sr + 4*lg;
  const bool isx = (ch == 0);
  const bool isg = (sr == 3);

  const float h = ts[1] - ts[0];
  f32x4 z4 = {0.f,0.f,0.f,0.f};
  f32x4 Pfr[2], Qfr[2], APd[2], APT[2], APdX, XRv;
  s16x8 aA[2], aRC[2], aC[2], bA[2][2];
  f32x4 y1v = z4, y2v = z4;
  #pragma unroll
  for (int c2 = 0; c2 < 2; ++c2) { Pfr[c2]=z4; Qfr[c2]=z4; APd[c2]=z4; APT[c2]=z4; }
  APdX = z4;

  #pragma unroll
  for (int c2 = 0; c2 < 2; ++c2)
    #pragma unroll
    for (int r = 0; r < 4; ++r) {
      int row = 16*sr + 4*lg + r, col = 16*(2*ch + c2) + lc;
      Pfr[c2][r] = P0g[row*64 + col];
      Qfr[c2][r] = Qg [row*64 + col];
    }
  #pragma unroll
  for (int kb = 0; kb < 2; ++kb) {
    aA [kb] = load_fragT<HYP>(sh.Ab,  PP, 16*sr, 32*kb);
    aRC[kb] = load_fragT<HYP>(sh.RCb, PP, 16*ch, 32*kb);
    aC [kb] = load_fragT<HYP>(sh.Cb,  PP, 16*ch, 32*kb);
    #pragma unroll
    for (int c2 = 0; c2 < 2; ++c2)
      bA[c2][kb] = load_fragT<HYP>(sh.Ab, PP, 16*(2*ch + c2), 32*kb);
  }
  XRv = *(const f32x4*)&x0g[rowbase];
  if (isg) {
    y1v = *(const f32x4*)&ys[16*ch + 4*lg];
    y2v = *(const f32x4*)&ys[NO + 16*ch + 4*lg];
  }
  if (tid < 64) {
    out[tid] = x0g[tid];
    sh.Pib[64*PP + tid] = f2bf(x0g[tid]);   // xi row = x0
    const f32x4* bf4 = (const f32x4*)&sh.Bf[tid*16];
    const f32x4* up4 = (const f32x4*)us;
    float bu = 0.f;
    #pragma unroll
    for (int m4 = 0; m4 < 4; ++m4) {
      f32x4 b = bf4[m4], u = up4[m4];
      bu += b.x*u.x + b.y*u.y + b.z*u.z + b.w*u.w;
    }
    sh.BUB[0][tid] = bu;
  }
  // zero the augmentation pads (rows 65-79 Pib incl row-64 pad cols, rows 64-79 GTb)
  for (int idx = tid; idx < 15*PP; idx += 512) sh.Pib[65*PP + idx] = 0;
  if (tid < PP - 64) sh.Pib[64*PP + 64 + tid] = 0;
  for (int idx = tid; idx < 16*PK; idx += 512) sh.GTb[64*PK + idx] = 0;
  __syncthreads();

  for (int t = 0; t < TN - 1; ++t) {
    #pragma unroll
    for (int st = 0; st < 6; ++st) {
      // ================= PHASE A =================
      s16x8 am;
      if (t > 0 || st > 0) {
        am = load_fragT<HYP>(sh.KKb, PK, 16*sr, 0);
        // ---- P-side: M, kP[ps], stage combine, pack Pi ----
        #pragma unroll
        for (int c2 = 0; c2 < 2; ++c2) {
          const int ct = 2*ch + c2;
          s16x8 bg = load_fragT<HYP>(sh.GTb, PK, 16*ct, 0);
          f32x4 M = MFT<HYP>(am, bg, z4);
          f32x4 kPv;
          #pragma unroll
          for (int r = 0; r < 4; ++r) kPv[r] = APd[c2][r] + APT[c2][r] - M[r];
          float* kbase = &KPL[(size_t)(16*ct + lc) * PKP + 16*sr + 4*lg];
          f32x4 x;
          if (st == 0) {
            f32x4 k0v = *(const f32x4*)(kbase + 0*64*PKP);
            f32x4 k2v = *(const f32x4*)(kbase + 2*64*PKP);
            f32x4 k3v = *(const f32x4*)(kbase + 3*64*PKP);
            f32x4 k4v = *(const f32x4*)(kbase + 4*64*PKP);
            #pragma unroll
            for (int r = 0; r < 4; ++r)
              Pfr[c2][r] += h * (BW0*k0v[r] + BW2*k2v[r] + BW3*k3v[r]
                               + BW4*k4v[r] + BW5*kPv[r] + Qfr[c2][r]);
            x = Pfr[c2];
          } else {
            *(f32x4*)(kbase + (size_t)(st-1)*64*PKP) = kPv;
            #pragma unroll
            for (int r = 0; r < 4; ++r)
              x[r] = Pfr[c2][r] + (h * CTAB[st]) * Qfr[c2][r] + (h * ATAB[st][st-1]) * kPv[r];
            if (st >= 2) { f32x4 kv = *(const f32x4*)(kbase + 0*64*PKP);
              #pragma unroll
              for (int r = 0; r < 4; ++r) x[r] += (h * ATAB[st][0]) * kv[r]; }
            if (st >= 3) { f32x4 kv = *(const f32x4*)(kbase + 1*64*PKP);
              #pragma unroll
              for (int r = 0; r < 4; ++r) x[r] += (h * ATAB[st][1]) * kv[r]; }
            if (st >= 4) { f32x4 kv = *(const f32x4*)(kbase + 2*64*PKP);
              #pragma unroll
              for (int r = 0; r < 4; ++r) x[r] += (h * ATAB[st][2]) * kv[r]; }
            if (st >= 5) { f32x4 kv = *(const f32x4*)(kbase + 3*64*PKP);
              #pragma unroll
              for (int r = 0; r < 4; ++r) x[r] += (h * ATAB[st][3]) * kv[r]; }
          }
          uint2 pk; pk.x = pack2bf(x[0], x[1]); pk.y = pack2bf(x[2], x[3]);
          *(uint2*)&sh.Pib[(16*ct + lc)*PP + 16*sr + 4*lg] = pk;
        }
        // ---- x-side: kx[ps] via MFMA columns, state update, write xi row ----
        if (isx) {
          s16x8 bgX = load_fragT<HYP>(sh.GTb, PK, 64, 0);
          f32x4 MX = MFT<HYP>(am, bgX, z4);
          f32x4 kx = APdX + MX;
          {
            f32x4 bu1 = *(const f32x4*)&sh.BUB[t & 1][rowbase];
            if (st == 0) {
              kx += bu1;
            } else {
              const float cp = CTAB[st-1];
              if (cp != 0.f) {
                f32x4 bu2 = *(const f32x4*)&sh.BUB[(t + 1) & 1][rowbase];
                kx += (1.f - cp) * bu1 + cp * bu2;
              } else {
                kx += bu1;
              }
            }
          }
          f32x4 xiv;
          if (st == 0) {
            f32x4 k0 = *(const f32x4*)&sh.KXL[0][rowbase];
            f32x4 k2 = *(const f32x4*)&sh.KXL[2][rowbase];
            f32x4 k3 = *(const f32x4*)&sh.KXL[3][rowbase];
            f32x4 k4 = *(const f32x4*)&sh.KXL[4][rowbase];
            XRv += h * (BW0*k0 + BW2*k2 + BW3*k3 + BW4*k4 + BW5*kx);
            if (lc == 0) *(f32x4*)&out[(size_t)t*64 + rowbase] = XRv;
            xiv = XRv;
          } else {
            if (lc == 0) *(f32x4*)&sh.KXL[st-1][rowbase] = kx;
            xiv = XRv + (h * ATAB[st][st-1]) * kx;
            if (st >= 2 && ATAB[st][0] != 0.f) xiv += (h * ATAB[st][0]) * (*(const f32x4*)&sh.KXL[0][rowbase]);
            if (st >= 3 && ATAB[st][1] != 0.f) xiv += (h * ATAB[st][1]) * (*(const f32x4*)&sh.KXL[1][rowbase]);
            if (st >= 4 && ATAB[st][2] != 0.f) xiv += (h * ATAB[st][2]) * (*(const f32x4*)&sh.KXL[2][rowbase]);
            if (st >= 5 && ATAB[st][3] != 0.f) xiv += (h * ATAB[st][3]) * (*(const f32x4*)&sh.KXL[3][rowbase]);
          }
          if (lc == 0) {
            uint2 pk; pk.x = pack2bf(xiv[0], xiv[1]); pk.y = pack2bf(xiv[2], xiv[3]);
            *(uint2*)&sh.Pib[64*PP + rowbase] = pk;
          }
        }
      } else {
        // t==0, st==0: initial P pack; xi row already = x0 from init
        #pragma unroll
        for (int c2 = 0; c2 < 2; ++c2) {
          const int ct = 2*ch + c2;
          uint2 pk; pk.x = pack2bf(Pfr[c2][0], Pfr[c2][1]); pk.y = pack2bf(Pfr[c2][2], Pfr[c2][3]);
          *(uint2*)&sh.Pib[(16*ct + lc)*PP + 16*sr + 4*lg] = pk;
        }
      }
      __syncthreads();
      // ================= PHASE B =================
      {
        s16x8 aPi0 = load_fragT<HYP>(sh.Pib, PP, 16*sr, 0);
        s16x8 aPi1 = load_fragT<HYP>(sh.Pib, PP, 16*sr, 32);
        #pragma unroll
        for (int c2 = 0; c2 < 2; ++c2) {
          const int ct = 2*ch + c2;
          s16x8 bP0 = load_fragT<HYP>(sh.Pib, PP, 16*ct, 0);
          s16x8 bP1 = load_fragT<HYP>(sh.Pib, PP, 16*ct, 32);
          APd[c2] = MFT<HYP>(aA[1], bP1, MFT<HYP>(aA[0], bP0, z4));
          APT[c2] = MFT<HYP>(aPi1, bA[c2][1], MFT<HYP>(aPi0, bA[c2][0], z4));
        }
        f32x4 aK = MFT<HYP>(aRC[1], aPi1, MFT<HYP>(aRC[0], aPi0, z4));
        uint2 pkk; pkk.x = pack2bf(aK[0], aK[1]); pkk.y = pack2bf(aK[2], aK[3]);
        *(uint2*)&sh.KKb[(16*sr + lc)*PK + 16*ch + 4*lg] = pkk;
        f32x4 aG = MFT<HYP>(aC[1], aPi1, MFT<HYP>(aC[0], aPi0, z4));
        uint2 pkg; pkg.x = pack2bf(aG[0], aG[1]); pkg.y = pack2bf(aG[2], aG[3]);
        *(uint2*)&sh.GTb[(16*sr + lc)*PK + 16*ch + 4*lg] = pkg;
      }
      if (isx || isg) {
        s16x8 px0 = load_fragT<HYP>(sh.Pib, PP, 64, 0);
        s16x8 px1 = load_fragT<HYP>(sh.Pib, PP, 64, 32);
        if (isx) {
          APdX = MFT<HYP>(aA[1], px1, MFT<HYP>(aA[0], px0, z4));
        }
        if (isg) {
          f32x4 gx = MFT<HYP>(aC[1], px1, MFT<HYP>(aC[0], px0, z4));
          const float c = CTAB[st];
          f32x4 v;
          #pragma unroll
          for (int r = 0; r < 4; ++r) {
            float yc = (1.f - c) * y1v[r] + c * y2v[r];
            v[r] = yc - gx[r];
          }
          uint2 pk;
          if (lc == 0) { pk.x = pack2bf(v[0], v[1]); pk.y = pack2bf(v[2], v[3]); }
          else         { pk.x = 0u; pk.y = 0u; }
          *(uint2*)&sh.GTb[(64 + lc)*PK + 16*ch + 4*lg] = pk;   // row 64 = cxr, rows 65-79 = 0
        }
      }
      if (st == 0 && tid < 64) {
        const f32x4* bf4 = (const f32x4*)&sh.Bf[tid*16];
        const f32x4* up4 = (const f32x4*)(us + (size_t)(t + 1)*NI);
        float bu = 0.f;
        #pragma unroll
        for (int m4 = 0; m4 < 4; ++m4) {
          f32x4 b = bf4[m4], u = up4[m4];
          bu += b.x*u.x + b.y*u.y + b.z*u.z + b.w*u.w;
        }
        sh.BUB[(t + 1) & 1][tid] = bu;
      }
      __syncthreads();
    } // stages
    if (isg) {
      y1v = y2v;
      if (t + 2 < TN) y2v = *(const f32x4*)&ys[(size_t)(t + 2)*NO + 16*ch + 4*lg];
    }
  } // t

  // tail: slope k5 of last step + final x combine
  if (isx) {
    s16x8 am  = load_fragT<HYP>(sh.KKb, PK, 16*sr, 0);
    s16x8 bgX = load_fragT<HYP>(sh.GTb, PK, 64, 0);
    f32x4 MX = MFT<HYP>(am, bgX, z4);
    f32x4 kx = APdX + MX;
    kx += *(const f32x4*)&sh.BUB[(TN - 1) & 1][rowbase];   // c5 = 1 -> BU at t+1
    f32x4 k0 = *(const f32x4*)&sh.KXL[0][rowbase];
    f32x4 k2 = *(const f32x4*)&sh.KXL[2][rowbase];
    f32x4 k3 = *(const f32x4*)&sh.KXL[3][rowbase];
    f32x4 k4 = *(const f32x4*)&sh.KXL[4][rowbase];
    XRv += h * (BW0*k0 + BW2*k2 + BW3*k3 + BW4*k4 + BW5*kx);
    if (lc == 0) *(f32x4*)&out[(size_t)(TN - 1)*64 + rowbase] = XRv;
  }
}

__global__ __launch_bounds__(512, 1)
void kf_mfma9(const float* __restrict__ ts, const float* __restrict__ ys,
              const float* __restrict__ us, const float* __restrict__ Ag,
              const float* __restrict__ Bg, const float* __restrict__ Cg,
              const float* __restrict__ x0g, const float* __restrict__ P0g,
              const float* __restrict__ Qg, const float* __restrict__ Rg,
              float* __restrict__ out)
{
  extern __shared__ char dsm[];
  ShB& sh = *(ShB*)dsm;
  float* KPL = (float*)(dsm + SH_BASE);
  float* GJ  = KPL;
  const int tid = (int)threadIdx.x;
  const int wv = tid >> 6;
  const int lc = tid & 15, lg = (tid & 63) >> 4;

  for (int idx = tid; idx < 64*64; idx += 512) sh.Ab[(idx>>6)*PP + (idx&63)] = f2bf(Ag[idx]);
  for (int idx = tid; idx < 32*64; idx += 512) sh.Cb[(idx>>6)*PP + (idx&63)] = f2bf(Cg[idx]);
  for (int idx = tid; idx < 64*16; idx += 512) sh.Bf[idx] = Bg[idx];
  for (int idx = tid; idx < 32*64; idx += 512) {
    int r = idx >> 6, c = idx & 63;
    GJ[idx] = (c < 32) ? Rg[r*32 + c] : ((c - 32) == r ? 1.f : 0.f);
  }
  __syncthreads();
  for (int k2 = 0; k2 < 32; ++k2) {
    if (tid < 32) sh.FAC[tid] = GJ[tid*64 + k2];
    __syncthreads();
    const float pinv = 1.f / sh.FAC[k2];
    float oldv[4], vk[4];
    #pragma unroll
    for (int s = 0; s < 4; ++s) {
      int idx = tid + s*512;
      oldv[s] = GJ[idx];
      vk[s]   = GJ[k2*64 + (idx & 63)];
    }
    __syncthreads();
    #pragma unroll
    for (int s = 0; s < 4; ++s) {
      int idx = tid + s*512, i = idx >> 6;
      GJ[idx] = (i == k2) ? (oldv[s] * pinv) : (oldv[s] - sh.FAC[i] * (vk[s] * pinv));
    }
    __syncthreads();
  }
  for (int idx = tid; idx < 32*64; idx += 512) {
    int q = idx >> 6, k = idx & 63;
    float a = 0.f;
    for (int p = 0; p < 32; ++p) a += GJ[q*64 + 32 + p] * Cg[p*64 + k];
    sh.RCb[q*PP + k] = f2bf(a);
  }
  __syncthreads();
  __shared__ float Xref[256];
  if (tid < 256) {
    int r = tid >> 4, c = tid & 15;
    float a = 0.f;
    for (int k = 0; k < 32; ++k) a += bf2f(sh.Ab[r*PP + k]) * bf2f(sh.Ab[(16 + c)*PP + k]);
    Xref[tid] = a;
  }
  if (tid == 0) sh.HYP = -1;
  __syncthreads();
  for (int hh = 0; hh < 4; ++hh) {
    if (wv == 0) {
      s16x8 af = load_frag(sh.Ab, PP, 0, 0, hh);
      s16x8 bf = load_frag(sh.Ab, PP, 16, 0, hh);
      f32x4 z = {0.f,0.f,0.f,0.f};
      f32x4 d = MF(af, bf, z, hh);
      int ok = 1;
      #pragma unroll
      for (int r = 0; r < 4; ++r) {
        float rf = Xref[(lg*4 + r)*16 + lc];
        ok &= (fabsf(d[r] - rf) <= 1e-3f + 1e-2f * fabsf(rf)) ? 1 : 0;
      }
      if (__all(ok) && tid == 0) { if (sh.HYP < 0) sh.HYP = hh; }
    }
    __syncthreads();
  }
  const int sHyp = (sh.HYP < 0) ? 0 : sh.HYP;

  switch (sHyp) {
    case 0: scan_body<0>(sh, KPL, ts, ys, us, x0g, P0g, Qg, out); break;
    case 1: scan_body<1>(sh, KPL, ts, ys, us, x0g, P0g, Qg, out); break;
    case 2: scan_body<2>(sh, KPL, ts, ys, us, x0g, P0g, Qg, out); break;
    default: scan_body<3>(sh, KPL, ts, ys, us, x0g, P0g, Qg, out); break;
  }
}

extern "C" void kernel_launch(void* const* d_in, const int* in_sizes, int n_in,
                              void* d_out, int out_size, void* d_ws, size_t ws_size,
                              hipStream_t stream) {
  (void)in_sizes; (void)n_in; (void)out_size; (void)d_ws; (void)ws_size;
  const float* ts  = (const float*)d_in[0];
  const float* ys  = (const float*)d_in[1];
  const float* us  = (const float*)d_in[2];
  const float* A   = (const float*)d_in[3];
  const float* B   = (const float*)d_in[4];
  const float* C   = (const float*)d_in[5];
  const float* x0  = (const float*)d_in[6];
  const float* P0  = (const float*)d_in[7];
  const float* Q   = (const float*)d_in[8];
  const float* R   = (const float*)d_in[9];
  (void)hipFuncSetAttribute(reinterpret_cast<const void*>(kf_mfma9),
                            hipFuncAttributeMaxDynamicSharedMemorySize, (int)SH_TOTAL);
  hipLaunchKernelGGL(kf_mfma9, dim3(1), dim3(512), SH_TOTAL, stream,
                     ts, ys, us, A, B, C, x0, P0, Q, R, (float*)d_out);
}

// Round 13
// 7169.289 us; speedup vs baseline: 3.1763x; 1.0276x over previous
//
#include <hip/hip_runtime.h>

typedef float f32x4 __attribute__((ext_vector_type(4)));
typedef short s16x8 __attribute__((ext_vector_type(8)));
typedef short s16x4 __attribute__((ext_vector_type(4)));

namespace kf {
constexpr int TN = 1024, NS = 64, NO = 32, NI = 16;
constexpr int PP = 72;   // u16 pitch, 64-col bf16 arrays
constexpr int PK = 40;   // u16 pitch, 32-col bf16 arrays
constexpr int PKP = 68;  // f32 pitch for kP store (16B-granule stride 17, odd -> conflict-free)

constexpr float ATAB[6][5] = {
  {0.f,0.f,0.f,0.f,0.f},
  {(float)(1.0/5.0),0.f,0.f,0.f,0.f},
  {(float)(3.0/40.0),(float)(9.0/40.0),0.f,0.f,0.f},
  {(float)(44.0/45.0),(float)(-56.0/15.0),(float)(32.0/9.0),0.f,0.f},
  {(float)(19372.0/6561.0),(float)(-25360.0/2187.0),(float)(64448.0/6561.0),(float)(-212.0/729.0),0.f},
  {(float)(9017.0/3168.0),(float)(-355.0/33.0),(float)(46732.0/5247.0),(float)(49.0/176.0),(float)(-5103.0/18656.0)},
};
constexpr float CTAB[6] = {0.f,(float)(1.0/5.0),(float)(3.0/10.0),(float)(4.0/5.0),(float)(8.0/9.0),1.f};
constexpr float BW0=(float)(35.0/384.0), BW2=(float)(500.0/1113.0), BW3=(float)(125.0/192.0),
                BW4=(float)(-2187.0/6784.0), BW5=(float)(11.0/84.0);

struct ShB {
  unsigned short Pib[80*PP];   // Pi augmented: row 64 = xi, rows 65-79 = 0
  unsigned short Ab [64*PP];
  unsigned short Cb [32*PP];
  unsigned short RCb[32*PP];   // holds -(Rinv C): KKb then stores -K (M/kx folds)
  unsigned short KKb[64*PK];   // -K
  unsigned short GTb[80*PK];   // GT; row 64 = (C@xi - y_c), rows 65-79 = 0
  float Bf[64*16];
  float BUB[2][64];
  float KXL[5][64];
  float FAC[32];
  int HYP;
};
constexpr size_t SH_BASE  = (sizeof(ShB) + 255) & ~size_t(255);
constexpr size_t SH_TOTAL = SH_BASE + size_t(5*64*PKP)*4;
} // namespace kf
using namespace kf;

__device__ inline float bf2f(unsigned short u){
  unsigned int x = ((unsigned int)u) << 16; return __builtin_bit_cast(float, x);
}
__device__ inline unsigned short f2bf(float f){
  unsigned int x = __builtin_bit_cast(unsigned int, f);
  return (unsigned short)((x + 0x7fffu + ((x >> 16) & 1u)) >> 16);
}
// R11 post-mortem: hand-written v_cvt_pk_bf16_f32 asm produced NaN (suspected
// src->half order swap scrambling packed columns -> Riccati divergence) and is
// documented slower anyway (m240). Proven bit-twiddle RNE (R8/R9) kept.
__device__ __forceinline__ unsigned int pack2bf(float a, float b){
  return (unsigned int)f2bf(a) | ((unsigned int)f2bf(b) << 16);
}
__device__ inline s16x8 load_frag(const unsigned short* arr, int pitch, int row0, int k0, int hyp){
  const int l = (int)(threadIdx.x & 63), lc = l & 15, lg = l >> 4;
  const unsigned short* p = arr + (row0 + lc) * pitch + k0;
  if ((hyp & 1) == 0) {
    return *(const s16x8*)(p + lg * 8);
  } else {
    s16x4 a = *(const s16x4*)(p + lg * 4);
    s16x4 b = *(const s16x4*)(p + 16 + lg * 4);
    s16x8 r; r[0]=a[0]; r[1]=a[1]; r[2]=a[2]; r[3]=a[3]; r[4]=b[0]; r[5]=b[1]; r[6]=b[2]; r[7]=b[3];
    return r;
  }
}
__device__ inline f32x4 MF(s16x8 a, s16x8 b, f32x4 c, int hyp){
  if (hyp & 2) return __builtin_amdgcn_mfma_f32_16x16x32_bf16(b, a, c, 0, 0, 0);
  return __builtin_amdgcn_mfma_f32_16x16x32_bf16(a, b, c, 0, 0, 0);
}
template<int HYP>
__device__ __forceinline__ s16x8 load_fragT(const unsigned short* arr, int pitch, int row0, int k0){
  const int l = (int)(threadIdx.x & 63), lc = l & 15, lg = l >> 4;
  const unsigned short* p = arr + (row0 + lc) * pitch + k0;
  if constexpr ((HYP & 1) == 0) {
    return *(const s16x8*)(p + lg * 8);
  } else {
    s16x4 a = *(const s16x4*)(p + lg * 4);
    s16x4 b = *(const s16x4*)(p + 16 + lg * 4);
    s16x8 r; r[0]=a[0]; r[1]=a[1]; r[2]=a[2]; r[3]=a[3]; r[4]=b[0]; r[5]=b[1]; r[6]=b[2]; r[7]=b[3];
    return r;
  }
}
template<int HYP>
__device__ __forceinline__ f32x4 MFT(s16x8 a, s16x8 b, f32x4 c){
  if constexpr ((HYP & 2) != 0) return __builtin_amdgcn_mfma_f32_16x16x32_bf16(b, a, c, 0, 0, 0);
  else                          return __builtin_amdgcn_mfma_f32_16x16x32_bf16(a, b, c, 0, 0, 0);
}

// Algebra (audited R11->R12): RCb negated at init => KKb = -K. Then:
//   AP   = A@Pi + Pi@A^T  (one 4-MFMA accumulator chain)
//   kP   = MFMA(-K frag, GT frag, AP) = AP - K@G      (no VALU adds)
//   GTX row 64 stores (C@xi - y_c)  => kx = MFMA(-K, GTX, APdX) = A@xi + K(y-Cx)
template<int HYP>
__device__ __forceinline__ void scan_body(ShB& sh, float* __restrict__ KPL,
    const float* __restrict__ ts, const float* __restrict__ ys, const float* __restrict__ us,
    const float* __restrict__ x0g, const float* __restrict__ P0g, const float* __restrict__ Qg,
    float* __restrict__ out)
{
  const int tid = (int)threadIdx.x;
  const int w = tid >> 6, l = tid & 63;
  const int lc = l & 15, lg = l >> 4;
  const int sr = w & 3, ch = w >> 2;
  const int rowbase = 16*sr + 4*lg;
  const bool isx = (ch == 0);
  const bool isg = (sr == 3);

  const float h = ts[1] - ts[0];
  f32x4 z4 = {0.f,0.f,0.f,0.f};
  f32x4 Pfr[2], Qfr[2], AP[2], APdX, XRv;
  s16x8 aA[2], aRC[2], aC[2], bA[2][2];
  f32x4 y1v = z4, y2v = z4;
  #pragma unroll
  for (int c2 = 0; c2 < 2; ++c2) { Pfr[c2]=z4; Qfr[c2]=z4; AP[c2]=z4; }
  APdX = z4;

  #pragma unroll
  for (int c2 = 0; c2 < 2; ++c2)
    #pragma unroll
    for (int r = 0; r < 4; ++r) {
      int row = 16*sr + 4*lg + r, col = 16*(2*ch + c2) + lc;
      Pfr[c2][r] = P0g[row*64 + col];
      Qfr[c2][r] = Qg [row*64 + col];
    }
  #pragma unroll
  for (int kb = 0; kb < 2; ++kb) {
    aA [kb] = load_fragT<HYP>(sh.Ab,  PP, 16*sr, 32*kb);
    aRC[kb] = load_fragT<HYP>(sh.RCb, PP, 16*ch, 32*kb);
    aC [kb] = load_fragT<HYP>(sh.Cb,  PP, 16*ch, 32*kb);
    #pragma unroll
    for (int c2 = 0; c2 < 2; ++c2)
      bA[c2][kb] = load_fragT<HYP>(sh.Ab, PP, 16*(2*ch + c2), 32*kb);
  }
  XRv = *(const f32x4*)&x0g[rowbase];
  if (isg) {
    y1v = *(const f32x4*)&ys[16*ch + 4*lg];
    y2v = *(const f32x4*)&ys[NO + 16*ch + 4*lg];
  }
  if (tid < 64) {
    out[tid] = x0g[tid];
    sh.Pib[64*PP + tid] = f2bf(x0g[tid]);
    const f32x4* bf4 = (const f32x4*)&sh.Bf[tid*16];
    const f32x4* up4 = (const f32x4*)us;
    float bu = 0.f;
    #pragma unroll
    for (int m4 = 0; m4 < 4; ++m4) {
      f32x4 b = bf4[m4], u = up4[m4];
      bu += b.x*u.x + b.y*u.y + b.z*u.z + b.w*u.w;
    }
    sh.BUB[0][tid] = bu;
  }
  for (int idx = tid; idx < 15*PP; idx += 512) sh.Pib[65*PP + idx] = 0;
  if (tid < PP - 64) sh.Pib[64*PP + 64 + tid] = 0;
  for (int idx = tid; idx < 16*PK; idx += 512) sh.GTb[64*PK + idx] = 0;
  __syncthreads();

  for (int t = 0; t < TN - 1; ++t) {
    #pragma unroll
    for (int st = 0; st < 6; ++st) {
      // ================= PHASE A =================
      if (t > 0 || st > 0) {
        s16x8 am = load_fragT<HYP>(sh.KKb, PK, 16*sr, 0);   // -K rows
        // ---- P-side: kP = AP - M (MFMA-folded), stage combine, pack Pi ----
        #pragma unroll
        for (int c2 = 0; c2 < 2; ++c2) {
          const int ct = 2*ch + c2;
          s16x8 bg = load_fragT<HYP>(sh.GTb, PK, 16*ct, 0);
          f32x4 kPv = MFT<HYP>(am, bg, AP[c2]);             // AP + (-K)@G
          float* kbase = &KPL[(size_t)(16*ct + lc) * PKP + 16*sr + 4*lg];
          f32x4 x;
          if (st == 0) {
            f32x4 k0v = *(const f32x4*)(kbase + 0*64*PKP);
            f32x4 k2v = *(const f32x4*)(kbase + 2*64*PKP);
            f32x4 k3v = *(const f32x4*)(kbase + 3*64*PKP);
            f32x4 k4v = *(const f32x4*)(kbase + 4*64*PKP);
            #pragma unroll
            for (int r = 0; r < 4; ++r)
              Pfr[c2][r] += h * (BW0*k0v[r] + BW2*k2v[r] + BW3*k3v[r]
                               + BW4*k4v[r] + BW5*kPv[r] + Qfr[c2][r]);
            x = Pfr[c2];
          } else {
            *(f32x4*)(kbase + (size_t)(st-1)*64*PKP) = kPv;
            #pragma unroll
            for (int r = 0; r < 4; ++r)
              x[r] = Pfr[c2][r] + (h * CTAB[st]) * Qfr[c2][r] + (h * ATAB[st][st-1]) * kPv[r];
            if (st >= 2) { f32x4 kv = *(const f32x4*)(kbase + 0*64*PKP);
              #pragma unroll
              for (int r = 0; r < 4; ++r) x[r] += (h * ATAB[st][0]) * kv[r]; }
            if (st >= 3) { f32x4 kv = *(const f32x4*)(kbase + 1*64*PKP);
              #pragma unroll
              for (int r = 0; r < 4; ++r) x[r] += (h * ATAB[st][1]) * kv[r]; }
            if (st >= 4) { f32x4 kv = *(const f32x4*)(kbase + 2*64*PKP);
              #pragma unroll
              for (int r = 0; r < 4; ++r) x[r] += (h * ATAB[st][2]) * kv[r]; }
            if (st >= 5) { f32x4 kv = *(const f32x4*)(kbase + 3*64*PKP);
              #pragma unroll
              for (int r = 0; r < 4; ++r) x[r] += (h * ATAB[st][3]) * kv[r]; }
          }
          uint2 pk; pk.x = pack2bf(x[0], x[1]); pk.y = pack2bf(x[2], x[3]);
          *(uint2*)&sh.Pib[(16*ct + lc)*PP + 16*sr + 4*lg] = pk;
        }
        // ---- x-side: kx = MFMA(-K, (Cx - y), APdX) + Bu ----
        if (isx) {
          s16x8 bgX = load_fragT<HYP>(sh.GTb, PK, 64, 0);
          f32x4 kx = MFT<HYP>(am, bgX, APdX);               // A@xi + K(y-Cx)
          {
            f32x4 bu1 = *(const f32x4*)&sh.BUB[t & 1][rowbase];
            if (st == 0) {
              kx += bu1;
            } else {
              const float cp = CTAB[st-1];
              if (cp != 0.f) {
                f32x4 bu2 = *(const f32x4*)&sh.BUB[(t + 1) & 1][rowbase];
                kx += (1.f - cp) * bu1 + cp * bu2;
              } else {
                kx += bu1;
              }
            }
          }
          f32x4 xiv;
          if (st == 0) {
            f32x4 k0 = *(const f32x4*)&sh.KXL[0][rowbase];
            f32x4 k2 = *(const f32x4*)&sh.KXL[2][rowbase];
            f32x4 k3 = *(const f32x4*)&sh.KXL[3][rowbase];
            f32x4 k4 = *(const f32x4*)&sh.KXL[4][rowbase];
            XRv += h * (BW0*k0 + BW2*k2 + BW3*k3 + BW4*k4 + BW5*kx);
            if (lc == 0) *(f32x4*)&out[(size_t)t*64 + rowbase] = XRv;
            xiv = XRv;
          } else {
            if (lc == 0) *(f32x4*)&sh.KXL[st-1][rowbase] = kx;
            xiv = XRv + (h * ATAB[st][st-1]) * kx;
            if (st >= 2 && ATAB[st][0] != 0.f) xiv += (h * ATAB[st][0]) * (*(const f32x4*)&sh.KXL[0][rowbase]);
            if (st >= 3 && ATAB[st][1] != 0.f) xiv += (h * ATAB[st][1]) * (*(const f32x4*)&sh.KXL[1][rowbase]);
            if (st >= 4 && ATAB[st][2] != 0.f) xiv += (h * ATAB[st][2]) * (*(const f32x4*)&sh.KXL[2][rowbase]);
            if (st >= 5 && ATAB[st][3] != 0.f) xiv += (h * ATAB[st][3]) * (*(const f32x4*)&sh.KXL[3][rowbase]);
          }
          if (lc == 0) {
            uint2 pk; pk.x = pack2bf(xiv[0], xiv[1]); pk.y = pack2bf(xiv[2], xiv[3]);
            *(uint2*)&sh.Pib[64*PP + rowbase] = pk;
          }
        }
      } else {
        #pragma unroll
        for (int c2 = 0; c2 < 2; ++c2) {
          const int ct = 2*ch + c2;
          uint2 pk; pk.x = pack2bf(Pfr[c2][0], Pfr[c2][1]); pk.y = pack2bf(Pfr[c2][2], Pfr[c2][3]);
          *(uint2*)&sh.Pib[(16*ct + lc)*PP + 16*sr + 4*lg] = pk;
        }
      }
      __syncthreads();
      // ================= PHASE B =================
      {
        s16x8 aPi0 = load_fragT<HYP>(sh.Pib, PP, 16*sr, 0);
        s16x8 aPi1 = load_fragT<HYP>(sh.Pib, PP, 16*sr, 32);
        #pragma unroll
        for (int c2 = 0; c2 < 2; ++c2) {
          const int ct = 2*ch + c2;
          s16x8 bP0 = load_fragT<HYP>(sh.Pib, PP, 16*ct, 0);
          s16x8 bP1 = load_fragT<HYP>(sh.Pib, PP, 16*ct, 32);
          // AP = A@Pi + Pi@A^T in one accumulator chain
          f32x4 acc = MFT<HYP>(aA[0], bP0, z4);
          acc = MFT<HYP>(aA[1], bP1, acc);
          acc = MFT<HYP>(aPi0, bA[c2][0], acc);
          AP[c2] = MFT<HYP>(aPi1, bA[c2][1], acc);
        }
        f32x4 aK = MFT<HYP>(aRC[1], aPi1, MFT<HYP>(aRC[0], aPi0, z4));   // = -K strip
        uint2 pkk; pkk.x = pack2bf(aK[0], aK[1]); pkk.y = pack2bf(aK[2], aK[3]);
        *(uint2*)&sh.KKb[(16*sr + lc)*PK + 16*ch + 4*lg] = pkk;
        f32x4 aG = MFT<HYP>(aC[1], aPi1, MFT<HYP>(aC[0], aPi0, z4));
        uint2 pkg; pkg.x = pack2bf(aG[0], aG[1]); pkg.y = pack2bf(aG[2], aG[3]);
        *(uint2*)&sh.GTb[(16*sr + lc)*PK + 16*ch + 4*lg] = pkg;
      }
      if (isx || isg) {
        s16x8 px0 = load_fragT<HYP>(sh.Pib, PP, 64, 0);
        s16x8 px1 = load_fragT<HYP>(sh.Pib, PP, 64, 32);
        if (isx) {
          APdX = MFT<HYP>(aA[1], px1, MFT<HYP>(aA[0], px0, z4));
        }
        if (isg) {
          f32x4 gx = MFT<HYP>(aC[1], px1, MFT<HYP>(aC[0], px0, z4));
          const float c = CTAB[st];
          f32x4 v;
          #pragma unroll
          for (int r = 0; r < 4; ++r) {
            float yc = (1.f - c) * y1v[r] + c * y2v[r];
            v[r] = gx[r] - yc;            // store (Cx - y): sign pairs with -K
          }
          uint2 pk;
          if (lc == 0) { pk.x = pack2bf(v[0], v[1]); pk.y = pack2bf(v[2], v[3]); }
          else         { pk.x = 0u; pk.y = 0u; }
          *(uint2*)&sh.GTb[(64 + lc)*PK + 16*ch + 4*lg] = pk;
        }
      }
      if (st == 0 && tid < 64) {
        const f32x4* bf4 = (const f32x4*)&sh.Bf[tid*16];
        const f32x4* up4 = (const f32x4*)(us + (size_t)(t + 1)*NI);
        float bu = 0.f;
        #pragma unroll
        for (int m4 = 0; m4 < 4; ++m4) {
          f32x4 b = bf4[m4], u = up4[m4];
          bu += b.x*u.x + b.y*u.y + b.z*u.z + b.w*u.w;
        }
        sh.BUB[(t + 1) & 1][tid] = bu;
      }
      __syncthreads();
    } // stages
    if (isg) {
      y1v = y2v;
      if (t + 2 < TN) y2v = *(const f32x4*)&ys[(size_t)(t + 2)*NO + 16*ch + 4*lg];
    }
  } // t

  // tail: slope k5 of last step + final x combine
  if (isx) {
    s16x8 am  = load_fragT<HYP>(sh.KKb, PK, 16*sr, 0);
    s16x8 bgX = load_fragT<HYP>(sh.GTb, PK, 64, 0);
    f32x4 kx = MFT<HYP>(am, bgX, APdX);
    kx += *(const f32x4*)&sh.BUB[(TN - 1) & 1][rowbase];
    f32x4 k0 = *(const f32x4*)&sh.KXL[0][rowbase];
    f32x4 k2 = *(const f32x4*)&sh.KXL[2][rowbase];
    f32x4 k3 = *(const f32x4*)&sh.KXL[3][rowbase];
    f32x4 k4 = *(const f32x4*)&sh.KXL[4][rowbase];
    XRv += h * (BW0*k0 + BW2*k2 + BW3*k3 + BW4*k4 + BW5*kx);
    if (lc == 0) *(f32x4*)&out[(size_t)(TN - 1)*64 + rowbase] = XRv;
  }
}

__global__ __launch_bounds__(512, 1)
void kf_mfma12(const float* __restrict__ ts, const float* __restrict__ ys,
               const float* __restrict__ us, const float* __restrict__ Ag,
               const float* __restrict__ Bg, const float* __restrict__ Cg,
               const float* __restrict__ x0g, const float* __restrict__ P0g,
               const float* __restrict__ Qg, const float* __restrict__ Rg,
               float* __restrict__ out)
{
  extern __shared__ char dsm[];
  ShB& sh = *(ShB*)dsm;
  float* KPL = (float*)(dsm + SH_BASE);
  float* GJ  = KPL;
  const int tid = (int)threadIdx.x;
  const int wv = tid >> 6;
  const int lc = tid & 15, lg = (tid & 63) >> 4;

  for (int idx = tid; idx < 64*64; idx += 512) sh.Ab[(idx>>6)*PP + (idx&63)] = f2bf(Ag[idx]);
  for (int idx = tid; idx < 32*64; idx += 512) sh.Cb[(idx>>6)*PP + (idx&63)] = f2bf(Cg[idx]);
  for (int idx = tid; idx < 64*16; idx += 512) sh.Bf[idx] = Bg[idx];
  for (int idx = tid; idx < 32*64; idx += 512) {
    int r = idx >> 6, c = idx & 63;
    GJ[idx] = (c < 32) ? Rg[r*32 + c] : ((c - 32) == r ? 1.f : 0.f);
  }
  __syncthreads();
  for (int k2 = 0; k2 < 32; ++k2) {
    if (tid < 32) sh.FAC[tid] = GJ[tid*64 + k2];
    __syncthreads();
    const float pinv = 1.f / sh.FAC[k2];
    float oldv[4], vk[4];
    #pragma unroll
    for (int s = 0; s < 4; ++s) {
      int idx = tid + s*512;
      oldv[s] = GJ[idx];
      vk[s]   = GJ[k2*64 + (idx & 63)];
    }
    __syncthreads();
    #pragma unroll
    for (int s = 0; s < 4; ++s) {
      int idx = tid + s*512, i = idx >> 6;
      GJ[idx] = (i == k2) ? (oldv[s] * pinv) : (oldv[s] - sh.FAC[i] * (vk[s] * pinv));
    }
    __syncthreads();
  }
  for (int idx = tid; idx < 32*64; idx += 512) {   // RCb = -(Rinv @ C)
    int q = idx >> 6, k = idx & 63;
    float a = 0.f;
    for (int p = 0; p < 32; ++p) a += GJ[q*64 + 32 + p] * Cg[p*64 + k];
    sh.RCb[q*PP + k] = f2bf(-a);
  }
  __syncthreads();
  __shared__ float Xref[256];
  if (tid < 256) {
    int r = tid >> 4, c = tid & 15;
    float a = 0.f;
    for (int k = 0; k < 32; ++k) a += bf2f(sh.Ab[r*PP + k]) * bf2f(sh.Ab[(16 + c)*PP + k]);
    Xref[tid] = a;
  }
  if (tid == 0) sh.HYP = -1;
  __syncthreads();
  for (int hh = 0; hh < 4; ++hh) {
    if (wv == 0) {
      s16x8 af = load_frag(sh.Ab, PP, 0, 0, hh);
      s16x8 bf = load_frag(sh.Ab, PP, 16, 0, hh);
      f32x4 z = {0.f,0.f,0.f,0.f};
      f32x4 d = MF(af, bf, z, hh);
      int ok = 1;
      #pragma unroll
      for (int r = 0; r < 4; ++r) {
        float rf = Xref[(lg*4 + r)*16 + lc];
        ok &= (fabsf(d[r] - rf) <= 1e-3f + 1e-2f * fabsf(rf)) ? 1 : 0;
      }
      if (__all(ok) && tid == 0) { if (sh.HYP < 0) sh.HYP = hh; }
    }
    __syncthreads();
  }
  const int sHyp = (sh.HYP < 0) ? 0 : sh.HYP;

  switch (sHyp) {
    case 0: scan_body<0>(sh, KPL, ts, ys, us, x0g, P0g, Qg, out); break;
    case 1: scan_body<1>(sh, KPL, ts, ys, us, x0g, P0g, Qg, out); break;
    case 2: scan_body<2>(sh, KPL, ts, ys, us, x0g, P0g, Qg, out); break;
    default: scan_body<3>(sh, KPL, ts, ys, us, x0g, P0g, Qg, out); break;
  }
}

extern "C" void kernel_launch(void* const* d_in, const int* in_sizes, int n_in,
                              void* d_out, int out_size, void* d_ws, size_t ws_size,
                              hipStream_t stream) {
  (void)in_sizes; (void)n_in; (void)out_size; (void)d_ws; (void)ws_size;
  const float* ts  = (const float*)d_in[0];
  const float* ys  = (const float*)d_in[1];
  const float* us  = (const float*)d_in[2];
  const float* A   = (const float*)d_in[3];
  const float* B   = (const float*)d_in[4];
  const float* C   = (const float*)d_in[5];
  const float* x0  = (const float*)d_in[6];
  const float* P0  = (const float*)d_in[7];
  const float* Q   = (const float*)d_in[8];
  const float* R   = (const float*)d_in[9];
  (void)hipFuncSetAttribute(reinterpret_cast<const void*>(kf_mfma12),
                            hipFuncAttributeMaxDynamicSharedMemorySize, (int)SH_TOTAL);
  hipLaunchKernelGGL(kf_mfma12, dim3(1), dim3(512), SH_TOTAL, stream,
                     ts, ys, us, A, B, C, x0, P0, Q, R, (float*)d_out);
}